// Round 1
// 688.341 us; speedup vs baseline: 1.0060x; 1.0060x over previous
//
#include <hip/hip_runtime.h>
#include <hip/hip_bf16.h>
#include <math.h>

using bf16 = __hip_bfloat16;
using short8 = __attribute__((ext_vector_type(8))) short;
using floatx4 = __attribute__((ext_vector_type(4))) float;

constexpr int B = 64;
constexpr int N = 197;
constexpr int C = 768;
constexpr int NH = 12;
constexpr int HD = 64;
constexpr int HID = 3072;
constexpr int M = B * N;          // 12608 = 197 * 64
constexpr int MPAD = 12672;       // 99 * 128
constexpr int MT = MPAD / 128;    // 99 M-tiles
constexpr int MTP = 104;          // padded to 8*13 for XCD swizzle
constexpr float EPS = 1e-5f;

__device__ __forceinline__ float b2f(bf16 v) { return __bfloat162float(v); }
__device__ __forceinline__ bf16 f2b(float v) { return __float2bfloat16(v); }

// async global->LDS, 16B/lane. HW dest = wave-uniform base + lane*16.
typedef const __attribute__((address_space(1))) unsigned int* gas1_t;
typedef __attribute__((address_space(3))) unsigned int* las3_t;
__device__ __forceinline__ void load_lds16(const bf16* g, bf16* l) {
  __builtin_amdgcn_global_load_lds((gas1_t)g, (las3_t)l, 16, 0, 0);
}

// ------- f32 weights -> bf16 MFMA-fragment layout --------------------------
// Wf[nb][kc][t'][lane*8]: slab of 512 bf16 = one B-fragment for a 16-col
// group (t') and one k-chunk (kc=32 k's). lane=quad*16+l16 reads elements
// W[n0 + t'*16 + l16][kc*32 + quad*8 + e] at lane*8 -> one coalesced 1 KB
// global_load_dwordx4 per fragment.
__global__ void cvt_wf_kernel(const float* __restrict__ src, bf16* __restrict__ dst,
                              int Nc, int K) {
  int i = blockIdx.x * 256 + threadIdx.x;     // one thread per 8-elem group
  int total = Nc * (K >> 3);
  if (i >= total) return;
  int k8 = i % (K >> 3);
  int n  = i / (K >> 3);
  int kc = k8 >> 2, quad = k8 & 3;
  int nb = n >> 7, nn = n & 127, tp = nn >> 4, l = nn & 15;
  int KC = K >> 5;
  size_t di = (((size_t)nb * KC + kc) * 8 + tp) * 512 + quad * 128 + l * 8;
  const float* s = src + (size_t)n * K + k8 * 8;
  #pragma unroll
  for (int e = 0; e < 8; ++e) dst[di + e] = f2b(s[e]);
}

// ---------------- block-wide sum over 256 threads (4 waves) ----------------
__device__ __forceinline__ float block_sum(float v, float* red) {
  #pragma unroll
  for (int off = 32; off >= 1; off >>= 1) v += __shfl_xor(v, off, 64);
  int w = threadIdx.x >> 6;
  if ((threadIdx.x & 63) == 0) red[w] = v;
  __syncthreads();
  float r = red[0] + red[1] + red[2] + red[3];
  __syncthreads();
  return r;
}

// ---------------- Kernel 1: LA pooling + channel MLP + fusion --------------
__global__ void la_pool_kernel(const float* __restrict__ x,
                               const float* __restrict__ f1w, const float* __restrict__ f1bias,
                               const float* __restrict__ f2w, const float* __restrict__ f2bias,
                               const float* __restrict__ vw,  const float* __restrict__ vbias,
                               float* __restrict__ fusion7) {
  int blk = blockIdx.x;
  int b = blk / 49, p = blk % 49;
  int h7 = p / 7, w7 = p % 7;
  int tid = threadIdx.x;
  int head = tid >> 4;     // 0..15
  int j = tid & 15;        // 0..15

  float sum = 0.f, mx = -3.0e38f;
  #pragma unroll
  for (int a = 0; a < 2; ++a) {
    #pragma unroll
    for (int bb = 0; bb < 2; ++bb) {
      int tok = 1 + (2 * h7 + a) * 14 + (2 * w7 + bb);
      const float* row = x + ((size_t)b * N + tok) * C + head * 48;
      #pragma unroll
      for (int s = 0; s < 3; ++s) {
        float v = row[j + 16 * s];
        sum += v;
        mx = fmaxf(mx, v);
      }
    }
  }
  #pragma unroll
  for (int off = 8; off >= 1; off >>= 1) {
    sum += __shfl_xor(sum, off, 64);
    mx = fmaxf(mx, __shfl_xor(mx, off, 64));
  }
  __shared__ float s_mean[16], s_max[16];
  if (j == 0) { s_mean[head] = sum / 192.f; s_max[head] = mx; }
  __syncthreads();
  if (tid < 16) {
    float hm = f1bias[0], hx = hm;
    #pragma unroll
    for (int h = 0; h < 16; ++h) {
      float w = f1w[h];
      hm += s_mean[h] * w;
      hx += s_max[h] * w;
    }
    hm = fmaxf(hm, 0.f);
    hx = fmaxf(hx, 0.f);
    float w2 = f2w[tid], b2v = f2bias[tid];
    float m   = hm * w2 + b2v;
    float mxv = hx * w2 + b2v;
    float fus = vw[0] * m + vw[1] * mxv + vbias[0];
    fusion7[((size_t)b * 16 + tid) * 49 + p] = fus;
  }
}

// ---------------- Kernel 2: gate (bilinear resize + sigmoid) + LN1 ---------
__global__ void gate_ln1_kernel(const float* __restrict__ x, const float* __restrict__ fusion7,
                                const float* __restrict__ g, const float* __restrict__ beta,
                                bf16* __restrict__ ln1) {
  int blk = blockIdx.x;
  int b = blk / N, n = blk % N;
  int tid = threadIdx.x;
  __shared__ float gates[16];
  __shared__ float red[4];

  if (tid < 16) {
    if (n > 0) {
      int hh = (n - 1) / 14, ww = (n - 1) % 14;
      float ch = fminf(fmaxf(hh * 0.5f - 0.25f, 0.f), 6.f);
      float cw = fminf(fmaxf(ww * 0.5f - 0.25f, 0.f), 6.f);
      int h0 = (int)floorf(ch); int h1 = min(h0 + 1, 6); float fh = ch - (float)h0;
      int w0 = (int)floorf(cw); int w1 = min(w0 + 1, 6); float fw = cw - (float)w0;
      const float* fp = fusion7 + ((size_t)b * 16 + tid) * 49;
      float v00 = fp[h0 * 7 + w0], v01 = fp[h0 * 7 + w1];
      float v10 = fp[h1 * 7 + w0], v11 = fp[h1 * 7 + w1];
      float v = (1.f - fh) * ((1.f - fw) * v00 + fw * v01)
              + fh        * ((1.f - fw) * v10 + fw * v11);
      gates[tid] = 1.f / (1.f + expf(-v));
    } else {
      gates[tid] = 0.f;   // cls token: multiplier (1+0) == identity
    }
  }
  __syncthreads();

  const float* xr = x + ((size_t)b * N + n) * C;
  float v[3];
  #pragma unroll
  for (int s = 0; s < 3; ++s) {
    int c = tid + 256 * s;
    v[s] = xr[c] * (1.f + gates[c / 48]);
  }
  float mu = block_sum(v[0] + v[1] + v[2], red) * (1.f / 768.f);
  float d0 = v[0] - mu, d1 = v[1] - mu, d2 = v[2] - mu;
  float var = block_sum(d0 * d0 + d1 * d1 + d2 * d2, red) * (1.f / 768.f);
  float rs = rsqrtf(var + EPS);
  bf16* orow = ln1 + ((size_t)b * N + n) * C;
  #pragma unroll
  for (int s = 0; s < 3; ++s) {
    int c = tid + 256 * s;
    orow[c] = f2b((v[s] - mu) * rs * g[c] + beta[c]);
  }
}

// ---------------- Kernel 3: LN over bf16 input -> bf16 ---------------------
__global__ void ln_bf16_kernel(const bf16* __restrict__ xin,
                               const float* __restrict__ g, const float* __restrict__ beta,
                               bf16* __restrict__ out) {
  int row = blockIdx.x;
  int tid = threadIdx.x;
  __shared__ float red[4];
  const bf16* xr = xin + (size_t)row * C;
  float v[3];
  #pragma unroll
  for (int s = 0; s < 3; ++s) v[s] = b2f(xr[tid + 256 * s]);
  float mu = block_sum(v[0] + v[1] + v[2], red) * (1.f / 768.f);
  float d0 = v[0] - mu, d1 = v[1] - mu, d2 = v[2] - mu;
  float var = block_sum(d0 * d0 + d1 * d1 + d2 * d2, red) * (1.f / 768.f);
  float rs = rsqrtf(var + EPS);
  bf16* orow = out + (size_t)row * C;
  #pragma unroll
  for (int s = 0; s < 3; ++s) {
    int c = tid + 256 * s;
    orow[c] = f2b((v[s] - mu) * rs * g[c] + beta[c]);
  }
}

// ---------------- Kernel 4: 128x128 tile, A+B via LDS dbuf -----------------
// C[M,Nc] = A[M,K]*W[Nc,K]^T + bias. W pre-shuffled to fragment layout (Wf).
// EPI: 0=bias, 1=bias+exact gelu.
// m97-faithful staging: both A (8 KB) and B (8 KB) staged per iteration via
// global_load_lds (4 issues/wave), fragments read back with ds_read_b128.
// Grid ordering: per-XCD column-chunked (W n-tiles fastest, then y) so the
// B chunk (<=2.3 MB) stays L2-resident and the A row panel is shared by the
// W consecutive blocks on the same XCD.
template <int EPI, int K>
__global__ void gemm128(const bf16* __restrict__ A, const bf16* __restrict__ Wf,
                        const float* __restrict__ bias,
                        const float* __restrict__ resF, const bf16* __restrict__ resB,
                        bf16* __restrict__ outB, float* __restrict__ outF, int Nc) {
  constexpr int KC = K >> 5;
  constexpr int CW = (K == 768) ? 6 : 3;   // column-chunk width (divides nx)
  constexpr int PERCH = 13 * CW;           // blocks per chunk per XCD
  int nx = Nc >> 7;
  int g = blockIdx.x;
  int c = g & 7;                 // XCD
  int t = g >> 3;                // stream index within XCD, [0, 13*nx)
  int ch = t / PERCH;
  int r  = t % PERCH;
  int j  = r / CW;
  int x  = ch * CW + (r % CW);
  int y  = c + 8 * j;
  if (y >= MT) return;                 // padded tail
  int m0 = y * 128;
  int n0 = x * 128;

  __shared__ __align__(16) bf16 sA[2][128 * 32];   // 8 KB per buffer
  __shared__ __align__(16) bf16 sB[2][8 * 512];    // 8 KB per buffer
  int tid = threadIdx.x;
  int wave = tid >> 6, lane = tid & 63, quad = lane >> 4, l16 = lane & 15;

  // A staging: one issue = 16 rows x 64B. wave w covers rows w*32..w*32+31.
  int ln16 = lane >> 2, seg = lane & 3;
  int sw = seg ^ ((ln16 >> 1) & 3);                 // swizzled chunk in row
  const bf16* gA = A + (size_t)(m0 + wave * 32 + ln16) * K + sw * 8;

  // B staging: slab (tp) of 512 bf16 = 1 KB, contiguous. wave w covers
  // slabs w*2, w*2+1. Per-lane src = slab + lane*16B; LDS fill is linear.
  const bf16* gB = Wf + ((size_t)(n0 >> 7) * KC) * 4096 + (size_t)(wave * 2) * 512 + lane * 8;

  int wm = (wave & 1) * 64, wn = (wave >> 1) * 64;  // wave quadrant
  int csw = (l16 >> 1) & 3;                         // fragment-read swizzle
  int tp0 = wn >> 4;                                // first B slab for wave

  floatx4 acc[4][4] = {};

  // prologue: stage A+B k-chunk 0 into buffer 0
  #pragma unroll
  for (int i = 0; i < 2; ++i) {
    load_lds16(gA + (size_t)(i * 16) * K, &sA[0][(wave * 32 + i * 16) * 32]);
    load_lds16(gB + i * 512, &sB[0][(wave * 2 + i) * 512]);
  }

  int p = 0;
  for (int kc = 0; kc < KC; ++kc, p ^= 1) {
    __syncthreads();                    // publishes buffers p
    if (kc + 1 < KC) {                  // prefetch chunk kc+1 into p^1
      #pragma unroll
      for (int i = 0; i < 2; ++i) {
        load_lds16(gA + (size_t)(i * 16) * K + (kc + 1) * 32,
                   &sA[p ^ 1][(wave * 32 + i * 16) * 32]);
        load_lds16(gB + (size_t)(kc + 1) * 4096 + i * 512,
                   &sB[p ^ 1][(wave * 2 + i) * 512]);
      }
    }
    short8 bw[4];
    #pragma unroll
    for (int t2 = 0; t2 < 4; ++t2)
      bw[t2] = *reinterpret_cast<const short8*>(&sB[p][(tp0 + t2) * 512 + lane * 8]);
    short8 af[4];
    #pragma unroll
    for (int s = 0; s < 4; ++s) {
      int row = wm + s * 16 + l16;
      af[s] = *reinterpret_cast<const short8*>(&sA[p][row * 32 + ((quad ^ csw) * 8)]);
    }
    #pragma unroll
    for (int s = 0; s < 4; ++s)
      #pragma unroll
      for (int t2 = 0; t2 < 4; ++t2)
        acc[s][t2] = __builtin_amdgcn_mfma_f32_16x16x32_bf16(af[s], bw[t2], acc[s][t2], 0, 0, 0);
  }

  #pragma unroll
  for (int t2 = 0; t2 < 4; ++t2) {
    int col = n0 + wn + t2 * 16 + l16;
    float bv = bias[col];
    #pragma unroll
    for (int s = 0; s < 4; ++s) {
      int rowb = m0 + wm + s * 16 + quad * 4;
      #pragma unroll
      for (int r2 = 0; r2 < 4; ++r2) {
        int row = rowb + r2;
        if (row < M) {
          float v = acc[s][t2][r2] + bv;
          if (EPI == 1) v = 0.5f * v * (1.f + erff(v * 0.7071067811865475f));
          size_t idx = (size_t)row * Nc + col;
          if (resF) v += resF[idx];
          if (resB) v += b2f(resB[idx]);
          if (outF) outF[idx] = v;
          if (outB) outB[idx] = f2b(v);
        }
      }
    }
  }
}

// ---------------- Kernel 5: MFMA attention, one block per (b, head) --------
__global__ void attn_mfma_kernel(const bf16* __restrict__ qkv, bf16* __restrict__ attn_o) {
  int bh = blockIdx.x;
  int h = bh % NH, b = bh / NH;
  int tid = threadIdx.x;
  int wave = tid >> 6, lane = tid & 63, quad = lane >> 4, l16 = lane & 15;

  __shared__ __align__(16) bf16 sVt[64][232];     // V^T: [d][m], m>=197 zero
  __shared__ __align__(16) bf16 sP[4][16][232];   // per-wave P: [q][m]

  const bf16* base = qkv + (size_t)b * N * 2304 + h * 64;

  {
    int d = tid & 63;
    for (int m = tid >> 6; m < 224; m += 4) {
      sVt[d][m] = (m < N) ? base[(size_t)m * 2304 + 1536 + d] : f2b(0.f);
    }
  }
  __syncthreads();

  const float scale = 0.125f;   // 64^-0.5

  for (int qt = wave; qt < 13; qt += 4) {
    int qr = min(qt * 16 + l16, N - 1);
    const bf16* qp = base + (size_t)qr * 2304;
    short8 aq0 = *reinterpret_cast<const short8*>(qp + quad * 8);
    short8 aq1 = *reinterpret_cast<const short8*>(qp + 32 + quad * 8);

    floatx4 s[13];
    #pragma unroll
    for (int kt = 0; kt < 13; ++kt) {
      int kr = min(kt * 16 + l16, N - 1);
      const bf16* kp = base + (size_t)kr * 2304 + 768;
      short8 bk0 = *reinterpret_cast<const short8*>(kp + quad * 8);
      short8 bk1 = *reinterpret_cast<const short8*>(kp + 32 + quad * 8);
      floatx4 acc = floatx4{0.f, 0.f, 0.f, 0.f};
      acc = __builtin_amdgcn_mfma_f32_16x16x32_bf16(aq0, bk0, acc, 0, 0, 0);
      acc = __builtin_amdgcn_mfma_f32_16x16x32_bf16(aq1, bk1, acc, 0, 0, 0);
      s[kt] = acc;
    }

    bool cv[13];
    #pragma unroll
    for (int kt = 0; kt < 13; ++kt) cv[kt] = (kt * 16 + l16) < N;

    float mx[4] = {-3.0e38f, -3.0e38f, -3.0e38f, -3.0e38f};
    #pragma unroll
    for (int kt = 0; kt < 13; ++kt) {
      #pragma unroll
      for (int r = 0; r < 4; ++r) {
        float sv = s[kt][r] * scale;
        s[kt][r] = sv;
        if (cv[kt]) mx[r] = fmaxf(mx[r], sv);
      }
    }
    #pragma unroll
    for (int off = 8; off >= 1; off >>= 1) {
      #pragma unroll
      for (int r = 0; r < 4; ++r) mx[r] = fmaxf(mx[r], __shfl_xor(mx[r], off, 64));
    }
    float sum[4] = {0.f, 0.f, 0.f, 0.f};
    #pragma unroll
    for (int kt = 0; kt < 13; ++kt) {
      #pragma unroll
      for (int r = 0; r < 4; ++r) {
        float e = cv[kt] ? expf(s[kt][r] - mx[r]) : 0.f;
        s[kt][r] = e;
        sum[r] += e;
      }
    }
    #pragma unroll
    for (int off = 8; off >= 1; off >>= 1) {
      #pragma unroll
      for (int r = 0; r < 4; ++r) sum[r] += __shfl_xor(sum[r], off, 64);
    }
    float inv[4];
    #pragma unroll
    for (int r = 0; r < 4; ++r) inv[r] = 1.f / sum[r];

    #pragma unroll
    for (int kt = 0; kt < 13; ++kt) {
      #pragma unroll
      for (int r = 0; r < 4; ++r)
        sP[wave][quad * 4 + r][kt * 16 + l16] = f2b(s[kt][r]);
    }
    #pragma unroll
    for (int r = 0; r < 4; ++r)
      sP[wave][quad * 4 + r][208 + l16] = f2b(0.f);

    floatx4 o[4] = {floatx4{0,0,0,0}, floatx4{0,0,0,0}, floatx4{0,0,0,0}, floatx4{0,0,0,0}};
    #pragma unroll
    for (int c = 0; c < 7; ++c) {
      short8 ap = *reinterpret_cast<const short8*>(&sP[wave][l16][c * 32 + quad * 8]);
      #pragma unroll
      for (int t = 0; t < 4; ++t) {
        short8 bv = *reinterpret_cast<const short8*>(&sVt[t * 16 + l16][c * 32 + quad * 8]);
        o[t] = __builtin_amdgcn_mfma_f32_16x16x32_bf16(ap, bv, o[t], 0, 0, 0);
      }
    }

    #pragma unroll
    for (int t = 0; t < 4; ++t) {
      #pragma unroll
      for (int r = 0; r < 4; ++r) {
        int qrow = qt * 16 + quad * 4 + r;
        if (qrow < N)
          attn_o[((size_t)b * N + qrow) * C + h * 64 + t * 16 + l16] = f2b(o[t][r] * inv[r]);
      }
    }
  }
}

// ---------------- host-side orchestration ----------------------------------
extern "C" void kernel_launch(void* const* d_in, const int* in_sizes, int n_in,
                              void* d_out, int out_size, void* d_ws, size_t ws_size,
                              hipStream_t stream) {
  (void)in_sizes; (void)n_in; (void)out_size; (void)ws_size;
  const float* x       = (const float*)d_in[0];
  const float* norm1_g = (const float*)d_in[1];
  const float* norm1_b = (const float*)d_in[2];
  const float* qkv_w   = (const float*)d_in[3];
  const float* qkv_b   = (const float*)d_in[4];
  const float* proj_w  = (const float*)d_in[5];
  const float* proj_b  = (const float*)d_in[6];
  const float* norm2_g = (const float*)d_in[7];
  const float* norm2_b = (const float*)d_in[8];
  const float* fc1_w   = (const float*)d_in[9];
  const float* fc1_b   = (const float*)d_in[10];
  const float* fc2_w   = (const float*)d_in[11];
  const float* fc2_b   = (const float*)d_in[12];
  const float* f1_w    = (const float*)d_in[13];
  const float* f1_b    = (const float*)d_in[14];
  const float* f2_w    = (const float*)d_in[15];
  const float* f2_b    = (const float*)d_in[16];
  const float* v_w     = (const float*)d_in[17];
  const float* v_b     = (const float*)d_in[18];
  float* out = (float*)d_out;

  char* ws = (char*)d_ws;
  // ws layout (~131.2 MB). Activation buffers padded to MPAD=12672 rows.
  float* fusion7 = (float*)(ws + 0);                //    200,704
  bf16*  qkv_wf  = (bf16*)(ws + 262144);            //  3,538,944
  bf16*  proj_wf = (bf16*)(ws + 3801088);           //  1,179,648
  bf16*  fc1_wf  = (bf16*)(ws + 4980736);           //  4,718,592
  bf16*  fc2_wf  = (bf16*)(ws + 9699328);           //  4,718,592
  bf16*  ln1     = (bf16*)(ws + 14417920);          // 19,464,192 (MPAD x 768; reused: attn_o, ln2)
  bf16*  attn_o  = ln1;
  bf16*  ln2     = ln1;
  bf16*  qkvb    = (bf16*)(ws + 33882112);          // 77,856,768 (qkv MPADx2304; reused hbuf MPADx3072)
  bf16*  hbuf    = qkvb;
  bf16*  x2b     = (bf16*)(ws + 111738880);         // 19,464,192 (MPAD x 768 bf16) -> end 131,203,072

  cvt_wf_kernel<<<(2304 * 96 + 255) / 256, 256, 0, stream>>>(qkv_w, qkv_wf, 2304, 768);
  cvt_wf_kernel<<<(768 * 96 + 255) / 256, 256, 0, stream>>>(proj_w, proj_wf, 768, 768);
  cvt_wf_kernel<<<(3072 * 96 + 255) / 256, 256, 0, stream>>>(fc1_w, fc1_wf, 3072, 768);
  cvt_wf_kernel<<<(768 * 384 + 255) / 256, 256, 0, stream>>>(fc2_w, fc2_wf, 768, 3072);

  la_pool_kernel<<<B * 49, 256, 0, stream>>>(x, f1_w, f1_b, f2_w, f2_b, v_w, v_b, fusion7);
  gate_ln1_kernel<<<B * N, 256, 0, stream>>>(x, fusion7, norm1_g, norm1_b, ln1);
  // qkv: (M x 768) x (2304 x 768)^T -> bf16
  gemm128<0, 768><<<(2304 / 128) * MTP, 256, 0, stream>>>(
      ln1, qkv_wf, qkv_b, nullptr, nullptr, qkvb, nullptr, 2304);
  attn_mfma_kernel<<<B * NH, 256, 0, stream>>>(qkvb, attn_o);
  // proj + residual(x f32) -> x2b (bf16)
  gemm128<0, 768><<<(768 / 128) * MTP, 256, 0, stream>>>(
      attn_o, proj_wf, proj_b, x, nullptr, x2b, nullptr, 768);
  ln_bf16_kernel<<<M, 256, 0, stream>>>(x2b, norm2_g, norm2_b, ln2);
  // fc1 + gelu -> hbuf (bf16)
  gemm128<1, 768><<<(HID / 128) * MTP, 256, 0, stream>>>(
      ln2, fc1_wf, fc1_b, nullptr, nullptr, hbuf, nullptr, HID);
  // fc2 + residual(x2b bf16) -> out (f32)
  gemm128<0, 3072><<<(768 / 128) * MTP, 256, 0, stream>>>(
      hbuf, fc2_wf, fc2_b, nullptr, x2b, nullptr, out, 768);
}

// Round 2
// 627.694 us; speedup vs baseline: 1.1032x; 1.0966x over previous
//
#include <hip/hip_runtime.h>
#include <hip/hip_bf16.h>
#include <math.h>

using bf16 = __hip_bfloat16;
using short8 = __attribute__((ext_vector_type(8))) short;
using floatx4 = __attribute__((ext_vector_type(4))) float;

constexpr int B = 64;
constexpr int N = 197;
constexpr int C = 768;
constexpr int NH = 12;
constexpr int HD = 64;
constexpr int HID = 3072;
constexpr int M = B * N;          // 12608 = 197 * 64
constexpr int MPAD = 12672;       // 99 * 128
constexpr int MT = MPAD / 128;    // 99 M-tiles
constexpr int MTP = 104;          // padded to 8*13 for XCD swizzle
constexpr float EPS = 1e-5f;

__device__ __forceinline__ float b2f(bf16 v) { return __bfloat162float(v); }
__device__ __forceinline__ bf16 f2b(float v) { return __float2bfloat16(v); }

// async global->LDS, 16B/lane. HW dest = wave-uniform base + lane*16.
typedef const __attribute__((address_space(1))) unsigned int* gas1_t;
typedef __attribute__((address_space(3))) unsigned int* las3_t;
__device__ __forceinline__ void load_lds16(const bf16* g, bf16* l) {
  __builtin_amdgcn_global_load_lds((gas1_t)g, (las3_t)l, 16, 0, 0);
}

// ------- f32 weights -> bf16 MFMA-fragment layout --------------------------
// Wf[nb][kc][t'][lane*8]: slab of 512 bf16 = one B-fragment for a 16-col
// group (t') and one k-chunk (kc=32 k's). lane=quad*16+l16 reads elements
// W[n0 + t'*16 + l16][kc*32 + quad*8 + e] at lane*8 -> one coalesced 1 KB
// global_load_dwordx4 per fragment.
__global__ void cvt_wf_kernel(const float* __restrict__ src, bf16* __restrict__ dst,
                              int Nc, int K) {
  int i = blockIdx.x * 256 + threadIdx.x;     // one thread per 8-elem group
  int total = Nc * (K >> 3);
  if (i >= total) return;
  int k8 = i % (K >> 3);
  int n  = i / (K >> 3);
  int kc = k8 >> 2, quad = k8 & 3;
  int nb = n >> 7, nn = n & 127, tp = nn >> 4, l = nn & 15;
  int KC = K >> 5;
  size_t di = (((size_t)nb * KC + kc) * 8 + tp) * 512 + quad * 128 + l * 8;
  const float* s = src + (size_t)n * K + k8 * 8;
  #pragma unroll
  for (int e = 0; e < 8; ++e) dst[di + e] = f2b(s[e]);
}

// ---------------- block-wide sum over 256 threads (4 waves) ----------------
__device__ __forceinline__ float block_sum(float v, float* red) {
  #pragma unroll
  for (int off = 32; off >= 1; off >>= 1) v += __shfl_xor(v, off, 64);
  int w = threadIdx.x >> 6;
  if ((threadIdx.x & 63) == 0) red[w] = v;
  __syncthreads();
  float r = red[0] + red[1] + red[2] + red[3];
  __syncthreads();
  return r;
}

// ---------------- Kernel 1: LA pooling + channel MLP + fusion --------------
__global__ void la_pool_kernel(const float* __restrict__ x,
                               const float* __restrict__ f1w, const float* __restrict__ f1bias,
                               const float* __restrict__ f2w, const float* __restrict__ f2bias,
                               const float* __restrict__ vw,  const float* __restrict__ vbias,
                               float* __restrict__ fusion7) {
  int blk = blockIdx.x;
  int b = blk / 49, p = blk % 49;
  int h7 = p / 7, w7 = p % 7;
  int tid = threadIdx.x;
  int head = tid >> 4;     // 0..15
  int j = tid & 15;        // 0..15

  float sum = 0.f, mx = -3.0e38f;
  #pragma unroll
  for (int a = 0; a < 2; ++a) {
    #pragma unroll
    for (int bb = 0; bb < 2; ++bb) {
      int tok = 1 + (2 * h7 + a) * 14 + (2 * w7 + bb);
      const float* row = x + ((size_t)b * N + tok) * C + head * 48;
      #pragma unroll
      for (int s = 0; s < 3; ++s) {
        float v = row[j + 16 * s];
        sum += v;
        mx = fmaxf(mx, v);
      }
    }
  }
  #pragma unroll
  for (int off = 8; off >= 1; off >>= 1) {
    sum += __shfl_xor(sum, off, 64);
    mx = fmaxf(mx, __shfl_xor(mx, off, 64));
  }
  __shared__ float s_mean[16], s_max[16];
  if (j == 0) { s_mean[head] = sum / 192.f; s_max[head] = mx; }
  __syncthreads();
  if (tid < 16) {
    float hm = f1bias[0], hx = hm;
    #pragma unroll
    for (int h = 0; h < 16; ++h) {
      float w = f1w[h];
      hm += s_mean[h] * w;
      hx += s_max[h] * w;
    }
    hm = fmaxf(hm, 0.f);
    hx = fmaxf(hx, 0.f);
    float w2 = f2w[tid], b2v = f2bias[tid];
    float m   = hm * w2 + b2v;
    float mxv = hx * w2 + b2v;
    float fus = vw[0] * m + vw[1] * mxv + vbias[0];
    fusion7[((size_t)b * 16 + tid) * 49 + p] = fus;
  }
}

// ---------------- Kernel 2: gate (bilinear resize + sigmoid) + LN1 ---------
__global__ void gate_ln1_kernel(const float* __restrict__ x, const float* __restrict__ fusion7,
                                const float* __restrict__ g, const float* __restrict__ beta,
                                bf16* __restrict__ ln1) {
  int blk = blockIdx.x;
  int b = blk / N, n = blk % N;
  int tid = threadIdx.x;
  __shared__ float gates[16];
  __shared__ float red[4];

  if (tid < 16) {
    if (n > 0) {
      int hh = (n - 1) / 14, ww = (n - 1) % 14;
      float ch = fminf(fmaxf(hh * 0.5f - 0.25f, 0.f), 6.f);
      float cw = fminf(fmaxf(ww * 0.5f - 0.25f, 0.f), 6.f);
      int h0 = (int)floorf(ch); int h1 = min(h0 + 1, 6); float fh = ch - (float)h0;
      int w0 = (int)floorf(cw); int w1 = min(w0 + 1, 6); float fw = cw - (float)w0;
      const float* fp = fusion7 + ((size_t)b * 16 + tid) * 49;
      float v00 = fp[h0 * 7 + w0], v01 = fp[h0 * 7 + w1];
      float v10 = fp[h1 * 7 + w0], v11 = fp[h1 * 7 + w1];
      float v = (1.f - fh) * ((1.f - fw) * v00 + fw * v01)
              + fh        * ((1.f - fw) * v10 + fw * v11);
      gates[tid] = 1.f / (1.f + expf(-v));
    } else {
      gates[tid] = 0.f;   // cls token: multiplier (1+0) == identity
    }
  }
  __syncthreads();

  const float* xr = x + ((size_t)b * N + n) * C;
  float v[3];
  #pragma unroll
  for (int s = 0; s < 3; ++s) {
    int c = tid + 256 * s;
    v[s] = xr[c] * (1.f + gates[c / 48]);
  }
  float mu = block_sum(v[0] + v[1] + v[2], red) * (1.f / 768.f);
  float d0 = v[0] - mu, d1 = v[1] - mu, d2 = v[2] - mu;
  float var = block_sum(d0 * d0 + d1 * d1 + d2 * d2, red) * (1.f / 768.f);
  float rs = rsqrtf(var + EPS);
  bf16* orow = ln1 + ((size_t)b * N + n) * C;
  #pragma unroll
  for (int s = 0; s < 3; ++s) {
    int c = tid + 256 * s;
    orow[c] = f2b((v[s] - mu) * rs * g[c] + beta[c]);
  }
}

// ---------------- Kernel 3: LN over bf16 input -> bf16 ---------------------
__global__ void ln_bf16_kernel(const bf16* __restrict__ xin,
                               const float* __restrict__ g, const float* __restrict__ beta,
                               bf16* __restrict__ out) {
  int row = blockIdx.x;
  int tid = threadIdx.x;
  __shared__ float red[4];
  const bf16* xr = xin + (size_t)row * C;
  float v[3];
  #pragma unroll
  for (int s = 0; s < 3; ++s) v[s] = b2f(xr[tid + 256 * s]);
  float mu = block_sum(v[0] + v[1] + v[2], red) * (1.f / 768.f);
  float d0 = v[0] - mu, d1 = v[1] - mu, d2 = v[2] - mu;
  float var = block_sum(d0 * d0 + d1 * d1 + d2 * d2, red) * (1.f / 768.f);
  float rs = rsqrtf(var + EPS);
  bf16* orow = out + (size_t)row * C;
  #pragma unroll
  for (int s = 0; s < 3; ++s) {
    int c = tid + 256 * s;
    orow[c] = f2b((v[s] - mu) * rs * g[c] + beta[c]);
  }
}

// ---------------- Kernel 4: 128x128 tile, counted-vmcnt pipeline -----------
// C[M,Nc] = A[M,K]*W[Nc,K]^T + bias. W pre-shuffled to fragment layout (Wf).
// EPI: 0=bias, 1=bias+exact gelu.
// T4 schedule: 3 LDS buffers, prefetch depth 2, per-iter
//   s_waitcnt vmcnt(4) lgkmcnt(0)  (waits ONLY the oldest chunk)
//   s_barrier
//   issue stage(kc+2)              (4 global_load_lds, stays in flight)
//   ds_read chunk kc; setprio(1); 16 MFMA; setprio(0)
// vmcnt never drains to 0 in the main loop (T4, m218). Safety: lgkmcnt(0)
// before the barrier retires every wave's ds_reads before any wave can
// re-stage that buffer; issue is after the barrier; 3 buffers => writer
// (kc+2) and previous-iter readers (kc-1) are separated by the barrier.
template <int EPI, int K>
__global__ void gemm128(const bf16* __restrict__ A, const bf16* __restrict__ Wf,
                        const float* __restrict__ bias,
                        const float* __restrict__ resF, const bf16* __restrict__ resB,
                        bf16* __restrict__ outB, float* __restrict__ outF, int Nc) {
  constexpr int KC = K >> 5;
  constexpr int CW = (K == 768) ? 6 : 3;   // column-chunk width (divides nx)
  constexpr int PERCH = 13 * CW;           // blocks per chunk per XCD
  int nx = Nc >> 7;
  int g = blockIdx.x;
  int c = g & 7;                 // XCD
  int t = g >> 3;                // stream index within XCD, [0, 13*nx)
  int ch = t / PERCH;
  int r  = t % PERCH;
  int j  = r / CW;
  int x  = ch * CW + (r % CW);
  int y  = c + 8 * j;
  if (y >= MT) return;                 // padded tail
  int m0 = y * 128;
  int n0 = x * 128;

  // 48 KB: 3 x 8KB A buffers + 3 x 8KB B buffers; reused as C-tile (34.8 KB)
  __shared__ __align__(16) char smem[49152];
  bf16* sA = (bf16*)smem;                  // [3][128*32]
  bf16* sB = (bf16*)(smem + 24576);        // [3][8*512]

  int tid = threadIdx.x;
  int wave = tid >> 6, lane = tid & 63, quad = lane >> 4, l16 = lane & 15;

  // A staging: one issue = 16 rows x 64B. wave w covers rows w*32..w*32+31.
  int ln16 = lane >> 2, seg = lane & 3;
  int sw = seg ^ ((ln16 >> 1) & 3);                 // swizzled chunk in row
  const bf16* gA = A + (size_t)(m0 + wave * 32 + ln16) * K + sw * 8;

  // B staging: slab (tp) of 512 bf16 = 1 KB, contiguous. wave w covers
  // slabs w*2, w*2+1. Per-lane src = slab + lane*16B; LDS fill is linear.
  const bf16* gB = Wf + ((size_t)(n0 >> 7) * KC) * 4096 + (size_t)(wave * 2) * 512 + lane * 8;

  int wm = (wave & 1) * 64, wn = (wave >> 1) * 64;  // wave quadrant
  int csw = (l16 >> 1) & 3;                         // fragment-read swizzle
  int tp0 = wn >> 4;                                // first B slab for wave

  floatx4 acc[4][4] = {};

  auto stage = [&](int kc, int bufi) {
    bf16* dA = sA + bufi * 4096 + (wave * 32) * 32;
    const bf16* sa = gA + kc * 32;
    load_lds16(sa, dA);
    load_lds16(sa + (size_t)16 * K, dA + 16 * 32);
    bf16* dB = sB + bufi * 4096 + (wave * 2) * 512;
    const bf16* sb = gB + (size_t)kc * 4096;
    load_lds16(sb, dB);
    load_lds16(sb + 512, dB + 512);
  };

  // prologue: chunks 0,1 -> buffers 0,1 (8 outstanding per wave)
  stage(0, 0);
  stage(1, 1);

  int bi = 0;
  for (int kc = 0; kc < KC; ++kc) {
    if (kc < KC - 1) {
      asm volatile("s_waitcnt vmcnt(4) lgkmcnt(0)" ::: "memory");
    } else {
      asm volatile("s_waitcnt vmcnt(0) lgkmcnt(0)" ::: "memory");
    }
    __builtin_amdgcn_s_barrier();
    __builtin_amdgcn_sched_barrier(0);

    if (kc + 2 < KC) {
      int bi2 = bi + 2; if (bi2 >= 3) bi2 -= 3;
      stage(kc + 2, bi2);
    }

    const bf16* aB = sA + bi * 4096;
    const bf16* bBp = sB + bi * 4096;
    short8 bw[4];
    #pragma unroll
    for (int t2 = 0; t2 < 4; ++t2)
      bw[t2] = *reinterpret_cast<const short8*>(bBp + (tp0 + t2) * 512 + lane * 8);
    short8 af[4];
    #pragma unroll
    for (int s = 0; s < 4; ++s) {
      int row = wm + s * 16 + l16;
      af[s] = *reinterpret_cast<const short8*>(aB + row * 32 + ((quad ^ csw) * 8));
    }
    __builtin_amdgcn_s_setprio(1);
    #pragma unroll
    for (int s = 0; s < 4; ++s)
      #pragma unroll
      for (int t2 = 0; t2 < 4; ++t2)
        acc[s][t2] = __builtin_amdgcn_mfma_f32_16x16x32_bf16(af[s], bw[t2], acc[s][t2], 0, 0, 0);
    __builtin_amdgcn_s_setprio(0);

    ++bi; if (bi >= 3) bi = 0;
  }

  if (!resF && !resB && outB) {
    // coalesced epilogue: acc -> LDS C-tile (bf16, stride 136) -> 16B stores
    __syncthreads();
    bf16* sC = (bf16*)smem;
    constexpr int SCS = 136;
    #pragma unroll
    for (int t2 = 0; t2 < 4; ++t2) {
      int col = wn + t2 * 16 + l16;
      float bv = bias[n0 + col];
      #pragma unroll
      for (int s = 0; s < 4; ++s) {
        int rowb = wm + s * 16 + quad * 4;
        #pragma unroll
        for (int r2 = 0; r2 < 4; ++r2) {
          float v = acc[s][t2][r2] + bv;
          if (EPI == 1) v = 0.5f * v * (1.f + erff(v * 0.7071067811865475f));
          sC[(rowb + r2) * SCS + col] = f2b(v);
        }
      }
    }
    __syncthreads();
    int rl = tid >> 4, cl = tid & 15;
    #pragma unroll
    for (int i = 0; i < 8; ++i) {
      int row = i * 16 + rl;
      int gr = m0 + row;
      if (gr < M) {
        short8 vv = *reinterpret_cast<const short8*>(sC + row * SCS + cl * 8);
        *reinterpret_cast<short8*>(outB + (size_t)gr * Nc + n0 + cl * 8) = vv;
      }
    }
  } else {
    #pragma unroll
    for (int t2 = 0; t2 < 4; ++t2) {
      int col = n0 + wn + t2 * 16 + l16;
      float bv = bias[col];
      #pragma unroll
      for (int s = 0; s < 4; ++s) {
        int rowb = m0 + wm + s * 16 + quad * 4;
        #pragma unroll
        for (int r2 = 0; r2 < 4; ++r2) {
          int row = rowb + r2;
          if (row < M) {
            float v = acc[s][t2][r2] + bv;
            if (EPI == 1) v = 0.5f * v * (1.f + erff(v * 0.7071067811865475f));
            size_t idx = (size_t)row * Nc + col;
            if (resF) v += resF[idx];
            if (resB) v += b2f(resB[idx]);
            if (outF) outF[idx] = v;
            if (outB) outB[idx] = f2b(v);
          }
        }
      }
    }
  }
}

// ---------------- Kernel 5: MFMA attention, one block per (b, head) --------
__global__ void attn_mfma_kernel(const bf16* __restrict__ qkv, bf16* __restrict__ attn_o) {
  int bh = blockIdx.x;
  int h = bh % NH, b = bh / NH;
  int tid = threadIdx.x;
  int wave = tid >> 6, lane = tid & 63, quad = lane >> 4, l16 = lane & 15;

  __shared__ __align__(16) bf16 sVt[64][232];     // V^T: [d][m], m>=197 zero
  __shared__ __align__(16) bf16 sP[4][16][232];   // per-wave P: [q][m]

  const bf16* base = qkv + (size_t)b * N * 2304 + h * 64;

  {
    int d = tid & 63;
    for (int m = tid >> 6; m < 224; m += 4) {
      sVt[d][m] = (m < N) ? base[(size_t)m * 2304 + 1536 + d] : f2b(0.f);
    }
  }
  __syncthreads();

  const float scale = 0.125f;   // 64^-0.5

  for (int qt = wave; qt < 13; qt += 4) {
    int qr = min(qt * 16 + l16, N - 1);
    const bf16* qp = base + (size_t)qr * 2304;
    short8 aq0 = *reinterpret_cast<const short8*>(qp + quad * 8);
    short8 aq1 = *reinterpret_cast<const short8*>(qp + 32 + quad * 8);

    floatx4 s[13];
    #pragma unroll
    for (int kt = 0; kt < 13; ++kt) {
      int kr = min(kt * 16 + l16, N - 1);
      const bf16* kp = base + (size_t)kr * 2304 + 768;
      short8 bk0 = *reinterpret_cast<const short8*>(kp + quad * 8);
      short8 bk1 = *reinterpret_cast<const short8*>(kp + 32 + quad * 8);
      floatx4 acc = floatx4{0.f, 0.f, 0.f, 0.f};
      acc = __builtin_amdgcn_mfma_f32_16x16x32_bf16(aq0, bk0, acc, 0, 0, 0);
      acc = __builtin_amdgcn_mfma_f32_16x16x32_bf16(aq1, bk1, acc, 0, 0, 0);
      s[kt] = acc;
    }

    bool cv[13];
    #pragma unroll
    for (int kt = 0; kt < 13; ++kt) cv[kt] = (kt * 16 + l16) < N;

    float mx[4] = {-3.0e38f, -3.0e38f, -3.0e38f, -3.0e38f};
    #pragma unroll
    for (int kt = 0; kt < 13; ++kt) {
      #pragma unroll
      for (int r = 0; r < 4; ++r) {
        float sv = s[kt][r] * scale;
        s[kt][r] = sv;
        if (cv[kt]) mx[r] = fmaxf(mx[r], sv);
      }
    }
    #pragma unroll
    for (int off = 8; off >= 1; off >>= 1) {
      #pragma unroll
      for (int r = 0; r < 4; ++r) mx[r] = fmaxf(mx[r], __shfl_xor(mx[r], off, 64));
    }
    float sum[4] = {0.f, 0.f, 0.f, 0.f};
    #pragma unroll
    for (int kt = 0; kt < 13; ++kt) {
      #pragma unroll
      for (int r = 0; r < 4; ++r) {
        float e = cv[kt] ? expf(s[kt][r] - mx[r]) : 0.f;
        s[kt][r] = e;
        sum[r] += e;
      }
    }
    #pragma unroll
    for (int off = 8; off >= 1; off >>= 1) {
      #pragma unroll
      for (int r = 0; r < 4; ++r) sum[r] += __shfl_xor(sum[r], off, 64);
    }
    float inv[4];
    #pragma unroll
    for (int r = 0; r < 4; ++r) inv[r] = 1.f / sum[r];

    #pragma unroll
    for (int kt = 0; kt < 13; ++kt) {
      #pragma unroll
      for (int r = 0; r < 4; ++r)
        sP[wave][quad * 4 + r][kt * 16 + l16] = f2b(s[kt][r]);
    }
    #pragma unroll
    for (int r = 0; r < 4; ++r)
      sP[wave][quad * 4 + r][208 + l16] = f2b(0.f);

    floatx4 o[4] = {floatx4{0,0,0,0}, floatx4{0,0,0,0}, floatx4{0,0,0,0}, floatx4{0,0,0,0}};
    #pragma unroll
    for (int c = 0; c < 7; ++c) {
      short8 ap = *reinterpret_cast<const short8*>(&sP[wave][l16][c * 32 + quad * 8]);
      #pragma unroll
      for (int t = 0; t < 4; ++t) {
        short8 bv = *reinterpret_cast<const short8*>(&sVt[t * 16 + l16][c * 32 + quad * 8]);
        o[t] = __builtin_amdgcn_mfma_f32_16x16x32_bf16(ap, bv, o[t], 0, 0, 0);
      }
    }

    #pragma unroll
    for (int t = 0; t < 4; ++t) {
      #pragma unroll
      for (int r = 0; r < 4; ++r) {
        int qrow = qt * 16 + quad * 4 + r;
        if (qrow < N)
          attn_o[((size_t)b * N + qrow) * C + h * 64 + t * 16 + l16] = f2b(o[t][r] * inv[r]);
      }
    }
  }
}

// ---------------- host-side orchestration ----------------------------------
extern "C" void kernel_launch(void* const* d_in, const int* in_sizes, int n_in,
                              void* d_out, int out_size, void* d_ws, size_t ws_size,
                              hipStream_t stream) {
  (void)in_sizes; (void)n_in; (void)out_size; (void)ws_size;
  const float* x       = (const float*)d_in[0];
  const float* norm1_g = (const float*)d_in[1];
  const float* norm1_b = (const float*)d_in[2];
  const float* qkv_w   = (const float*)d_in[3];
  const float* qkv_b   = (const float*)d_in[4];
  const float* proj_w  = (const float*)d_in[5];
  const float* proj_b  = (const float*)d_in[6];
  const float* norm2_g = (const float*)d_in[7];
  const float* norm2_b = (const float*)d_in[8];
  const float* fc1_w   = (const float*)d_in[9];
  const float* fc1_b   = (const float*)d_in[10];
  const float* fc2_w   = (const float*)d_in[11];
  const float* fc2_b   = (const float*)d_in[12];
  const float* f1_w    = (const float*)d_in[13];
  const float* f1_b    = (const float*)d_in[14];
  const float* f2_w    = (const float*)d_in[15];
  const float* f2_b    = (const float*)d_in[16];
  const float* v_w     = (const float*)d_in[17];
  const float* v_b     = (const float*)d_in[18];
  float* out = (float*)d_out;

  char* ws = (char*)d_ws;
  // ws layout (~131.2 MB). Activation buffers padded to MPAD=12672 rows.
  float* fusion7 = (float*)(ws + 0);                //    200,704
  bf16*  qkv_wf  = (bf16*)(ws + 262144);            //  3,538,944
  bf16*  proj_wf = (bf16*)(ws + 3801088);           //  1,179,648
  bf16*  fc1_wf  = (bf16*)(ws + 4980736);           //  4,718,592
  bf16*  fc2_wf  = (bf16*)(ws + 9699328);           //  4,718,592
  bf16*  ln1     = (bf16*)(ws + 14417920);          // 19,464,192 (MPAD x 768; reused: attn_o, ln2)
  bf16*  attn_o  = ln1;
  bf16*  ln2     = ln1;
  bf16*  qkvb    = (bf16*)(ws + 33882112);          // 77,856,768 (qkv MPADx2304; reused hbuf MPADx3072)
  bf16*  hbuf    = qkvb;
  bf16*  x2b     = (bf16*)(ws + 111738880);         // 19,464,192 (MPAD x 768 bf16) -> end 131,203,072

  cvt_wf_kernel<<<(2304 * 96 + 255) / 256, 256, 0, stream>>>(qkv_w, qkv_wf, 2304, 768);
  cvt_wf_kernel<<<(768 * 96 + 255) / 256, 256, 0, stream>>>(proj_w, proj_wf, 768, 768);
  cvt_wf_kernel<<<(3072 * 96 + 255) / 256, 256, 0, stream>>>(fc1_w, fc1_wf, 3072, 768);
  cvt_wf_kernel<<<(768 * 384 + 255) / 256, 256, 0, stream>>>(fc2_w, fc2_wf, 768, 3072);

  la_pool_kernel<<<B * 49, 256, 0, stream>>>(x, f1_w, f1_b, f2_w, f2_b, v_w, v_b, fusion7);
  gate_ln1_kernel<<<B * N, 256, 0, stream>>>(x, fusion7, norm1_g, norm1_b, ln1);
  // qkv: (M x 768) x (2304 x 768)^T -> bf16
  gemm128<0, 768><<<(2304 / 128) * MTP, 256, 0, stream>>>(
      ln1, qkv_wf, qkv_b, nullptr, nullptr, qkvb, nullptr, 2304);
  attn_mfma_kernel<<<B * NH, 256, 0, stream>>>(qkvb, attn_o);
  // proj + residual(x f32) -> x2b (bf16)
  gemm128<0, 768><<<(768 / 128) * MTP, 256, 0, stream>>>(
      attn_o, proj_wf, proj_b, x, nullptr, x2b, nullptr, 768);
  ln_bf16_kernel<<<M, 256, 0, stream>>>(x2b, norm2_g, norm2_b, ln2);
  // fc1 + gelu -> hbuf (bf16)
  gemm128<1, 768><<<(HID / 128) * MTP, 256, 0, stream>>>(
      ln2, fc1_wf, fc1_b, nullptr, nullptr, hbuf, nullptr, HID);
  // fc2 + residual(x2b bf16) -> out (f32)
  gemm128<0, 3072><<<(768 / 128) * MTP, 256, 0, stream>>>(
      hbuf, fc2_wf, fc2_b, nullptr, x2b, nullptr, out, 768);
}

// Round 3
// 547.232 us; speedup vs baseline: 1.2654x; 1.1470x over previous
//
#include <hip/hip_runtime.h>
#include <hip/hip_bf16.h>
#include <math.h>

using bf16 = __hip_bfloat16;
using short8 = __attribute__((ext_vector_type(8))) short;
using floatx4 = __attribute__((ext_vector_type(4))) float;

constexpr int B = 64;
constexpr int N = 197;
constexpr int C = 768;
constexpr int NH = 12;
constexpr int HD = 64;
constexpr int HID = 3072;
constexpr int M = B * N;          // 12608 = 197 * 64
constexpr int MPAD = 12672;       // 99 * 128
constexpr int MT = MPAD / 128;    // 99 M-tiles
constexpr int MTP = 104;          // padded to 8*13 for XCD swizzle
constexpr float EPS = 1e-5f;

__device__ __forceinline__ float b2f(bf16 v) { return __bfloat162float(v); }
__device__ __forceinline__ bf16 f2b(float v) { return __float2bfloat16(v); }

// async global->LDS, 16B/lane. HW dest = wave-uniform base + lane*16.
typedef const __attribute__((address_space(1))) unsigned int* gas1_t;
typedef __attribute__((address_space(3))) unsigned int* las3_t;
__device__ __forceinline__ void load_lds16(const bf16* g, bf16* l) {
  __builtin_amdgcn_global_load_lds((gas1_t)g, (las3_t)l, 16, 0, 0);
}

// ------- f32 weights -> bf16 MFMA-fragment layout --------------------------
__global__ void cvt_wf_kernel(const float* __restrict__ src, bf16* __restrict__ dst,
                              int Nc, int K) {
  int i = blockIdx.x * 256 + threadIdx.x;     // one thread per 8-elem group
  int total = Nc * (K >> 3);
  if (i >= total) return;
  int k8 = i % (K >> 3);
  int n  = i / (K >> 3);
  int kc = k8 >> 2, quad = k8 & 3;
  int nb = n >> 7, nn = n & 127, tp = nn >> 4, l = nn & 15;
  int KC = K >> 5;
  size_t di = (((size_t)nb * KC + kc) * 8 + tp) * 512 + quad * 128 + l * 8;
  const float* s = src + (size_t)n * K + k8 * 8;
  #pragma unroll
  for (int e = 0; e < 8; ++e) dst[di + e] = f2b(s[e]);
}

// ---------------- block-wide sum over 256 threads (4 waves) ----------------
__device__ __forceinline__ float block_sum(float v, float* red) {
  #pragma unroll
  for (int off = 32; off >= 1; off >>= 1) v += __shfl_xor(v, off, 64);
  int w = threadIdx.x >> 6;
  if ((threadIdx.x & 63) == 0) red[w] = v;
  __syncthreads();
  float r = red[0] + red[1] + red[2] + red[3];
  __syncthreads();
  return r;
}

// ---------------- Kernel 1: LA pooling + channel MLP + fusion --------------
__global__ void la_pool_kernel(const float* __restrict__ x,
                               const float* __restrict__ f1w, const float* __restrict__ f1bias,
                               const float* __restrict__ f2w, const float* __restrict__ f2bias,
                               const float* __restrict__ vw,  const float* __restrict__ vbias,
                               float* __restrict__ fusion7) {
  int blk = blockIdx.x;
  int b = blk / 49, p = blk % 49;
  int h7 = p / 7, w7 = p % 7;
  int tid = threadIdx.x;
  int head = tid >> 4;     // 0..15
  int j = tid & 15;        // 0..15

  float sum = 0.f, mx = -3.0e38f;
  #pragma unroll
  for (int a = 0; a < 2; ++a) {
    #pragma unroll
    for (int bb = 0; bb < 2; ++bb) {
      int tok = 1 + (2 * h7 + a) * 14 + (2 * w7 + bb);
      const float* row = x + ((size_t)b * N + tok) * C + head * 48;
      #pragma unroll
      for (int s = 0; s < 3; ++s) {
        float v = row[j + 16 * s];
        sum += v;
        mx = fmaxf(mx, v);
      }
    }
  }
  #pragma unroll
  for (int off = 8; off >= 1; off >>= 1) {
    sum += __shfl_xor(sum, off, 64);
    mx = fmaxf(mx, __shfl_xor(mx, off, 64));
  }
  __shared__ float s_mean[16], s_max[16];
  if (j == 0) { s_mean[head] = sum / 192.f; s_max[head] = mx; }
  __syncthreads();
  if (tid < 16) {
    float hm = f1bias[0], hx = hm;
    #pragma unroll
    for (int h = 0; h < 16; ++h) {
      float w = f1w[h];
      hm += s_mean[h] * w;
      hx += s_max[h] * w;
    }
    hm = fmaxf(hm, 0.f);
    hx = fmaxf(hx, 0.f);
    float w2 = f2w[tid], b2v = f2bias[tid];
    float m   = hm * w2 + b2v;
    float mxv = hx * w2 + b2v;
    float fus = vw[0] * m + vw[1] * mxv + vbias[0];
    fusion7[((size_t)b * 16 + tid) * 49 + p] = fus;
  }
}

// ---------------- Kernel 2: gate (bilinear resize + sigmoid) + LN1 ---------
__global__ void gate_ln1_kernel(const float* __restrict__ x, const float* __restrict__ fusion7,
                                const float* __restrict__ g, const float* __restrict__ beta,
                                bf16* __restrict__ ln1) {
  int blk = blockIdx.x;
  int b = blk / N, n = blk % N;
  int tid = threadIdx.x;
  __shared__ float gates[16];
  __shared__ float red[4];

  if (tid < 16) {
    if (n > 0) {
      int hh = (n - 1) / 14, ww = (n - 1) % 14;
      float ch = fminf(fmaxf(hh * 0.5f - 0.25f, 0.f), 6.f);
      float cw = fminf(fmaxf(ww * 0.5f - 0.25f, 0.f), 6.f);
      int h0 = (int)floorf(ch); int h1 = min(h0 + 1, 6); float fh = ch - (float)h0;
      int w0 = (int)floorf(cw); int w1 = min(w0 + 1, 6); float fw = cw - (float)w0;
      const float* fp = fusion7 + ((size_t)b * 16 + tid) * 49;
      float v00 = fp[h0 * 7 + w0], v01 = fp[h0 * 7 + w1];
      float v10 = fp[h1 * 7 + w0], v11 = fp[h1 * 7 + w1];
      float v = (1.f - fh) * ((1.f - fw) * v00 + fw * v01)
              + fh        * ((1.f - fw) * v10 + fw * v11);
      gates[tid] = 1.f / (1.f + expf(-v));
    } else {
      gates[tid] = 0.f;   // cls token: multiplier (1+0) == identity
    }
  }
  __syncthreads();

  const float* xr = x + ((size_t)b * N + n) * C;
  float v[3];
  #pragma unroll
  for (int s = 0; s < 3; ++s) {
    int c = tid + 256 * s;
    v[s] = xr[c] * (1.f + gates[c / 48]);
  }
  float mu = block_sum(v[0] + v[1] + v[2], red) * (1.f / 768.f);
  float d0 = v[0] - mu, d1 = v[1] - mu, d2 = v[2] - mu;
  float var = block_sum(d0 * d0 + d1 * d1 + d2 * d2, red) * (1.f / 768.f);
  float rs = rsqrtf(var + EPS);
  bf16* orow = ln1 + ((size_t)b * N + n) * C;
  #pragma unroll
  for (int s = 0; s < 3; ++s) {
    int c = tid + 256 * s;
    orow[c] = f2b((v[s] - mu) * rs * g[c] + beta[c]);
  }
}

// ---------------- Kernel 3: LN over bf16 input -> bf16 ---------------------
__global__ void ln_bf16_kernel(const bf16* __restrict__ xin,
                               const float* __restrict__ g, const float* __restrict__ beta,
                               bf16* __restrict__ out) {
  int row = blockIdx.x;
  int tid = threadIdx.x;
  __shared__ float red[4];
  const bf16* xr = xin + (size_t)row * C;
  float v[3];
  #pragma unroll
  for (int s = 0; s < 3; ++s) v[s] = b2f(xr[tid + 256 * s]);
  float mu = block_sum(v[0] + v[1] + v[2], red) * (1.f / 768.f);
  float d0 = v[0] - mu, d1 = v[1] - mu, d2 = v[2] - mu;
  float var = block_sum(d0 * d0 + d1 * d1 + d2 * d2, red) * (1.f / 768.f);
  float rs = rsqrtf(var + EPS);
  bf16* orow = out + (size_t)row * C;
  #pragma unroll
  for (int s = 0; s < 3; ++s) {
    int c = tid + 256 * s;
    orow[c] = f2b((v[s] - mu) * rs * g[c] + beta[c]);
  }
}

// ---------------- Kernel 4: 128x128 tile, counted-vmcnt pipeline -----------
// (unchanged from round 2 — T4 schedule, 3 buffers, vmcnt(4), setprio)
template <int EPI, int K>
__global__ void gemm128(const bf16* __restrict__ A, const bf16* __restrict__ Wf,
                        const float* __restrict__ bias,
                        const float* __restrict__ resF, const bf16* __restrict__ resB,
                        bf16* __restrict__ outB, float* __restrict__ outF, int Nc) {
  constexpr int KC = K >> 5;
  constexpr int CW = (K == 768) ? 6 : 3;   // column-chunk width (divides nx)
  constexpr int PERCH = 13 * CW;           // blocks per chunk per XCD
  int nx = Nc >> 7;
  int g = blockIdx.x;
  int c = g & 7;                 // XCD
  int t = g >> 3;                // stream index within XCD, [0, 13*nx)
  int ch = t / PERCH;
  int r  = t % PERCH;
  int j  = r / CW;
  int x  = ch * CW + (r % CW);
  int y  = c + 8 * j;
  if (y >= MT) return;                 // padded tail
  int m0 = y * 128;
  int n0 = x * 128;

  // 48 KB: 3 x 8KB A buffers + 3 x 8KB B buffers; reused as C-tile
  __shared__ __align__(16) char smem[49152];
  bf16* sA = (bf16*)smem;                  // [3][128*32]
  bf16* sB = (bf16*)(smem + 24576);        // [3][8*512]

  int tid = threadIdx.x;
  int wave = tid >> 6, lane = tid & 63, quad = lane >> 4, l16 = lane & 15;

  int ln16 = lane >> 2, seg = lane & 3;
  int sw = seg ^ ((ln16 >> 1) & 3);                 // swizzled chunk in row
  const bf16* gA = A + (size_t)(m0 + wave * 32 + ln16) * K + sw * 8;

  const bf16* gB = Wf + ((size_t)(n0 >> 7) * KC) * 4096 + (size_t)(wave * 2) * 512 + lane * 8;

  int wm = (wave & 1) * 64, wn = (wave >> 1) * 64;  // wave quadrant
  int csw = (l16 >> 1) & 3;                         // fragment-read swizzle
  int tp0 = wn >> 4;                                // first B slab for wave

  floatx4 acc[4][4] = {};

  auto stage = [&](int kc, int bufi) {
    bf16* dA = sA + bufi * 4096 + (wave * 32) * 32;
    const bf16* sa = gA + kc * 32;
    load_lds16(sa, dA);
    load_lds16(sa + (size_t)16 * K, dA + 16 * 32);
    bf16* dB = sB + bufi * 4096 + (wave * 2) * 512;
    const bf16* sb = gB + (size_t)kc * 4096;
    load_lds16(sb, dB);
    load_lds16(sb + 512, dB + 512);
  };

  // prologue: chunks 0,1 -> buffers 0,1 (8 outstanding per wave)
  stage(0, 0);
  stage(1, 1);

  int bi = 0;
  for (int kc = 0; kc < KC; ++kc) {
    if (kc < KC - 1) {
      asm volatile("s_waitcnt vmcnt(4) lgkmcnt(0)" ::: "memory");
    } else {
      asm volatile("s_waitcnt vmcnt(0) lgkmcnt(0)" ::: "memory");
    }
    __builtin_amdgcn_s_barrier();
    __builtin_amdgcn_sched_barrier(0);

    if (kc + 2 < KC) {
      int bi2 = bi + 2; if (bi2 >= 3) bi2 -= 3;
      stage(kc + 2, bi2);
    }

    const bf16* aB = sA + bi * 4096;
    const bf16* bBp = sB + bi * 4096;
    short8 bw[4];
    #pragma unroll
    for (int t2 = 0; t2 < 4; ++t2)
      bw[t2] = *reinterpret_cast<const short8*>(bBp + (tp0 + t2) * 512 + lane * 8);
    short8 af[4];
    #pragma unroll
    for (int s = 0; s < 4; ++s) {
      int row = wm + s * 16 + l16;
      af[s] = *reinterpret_cast<const short8*>(aB + row * 32 + ((quad ^ csw) * 8));
    }
    __builtin_amdgcn_s_setprio(1);
    #pragma unroll
    for (int s = 0; s < 4; ++s)
      #pragma unroll
      for (int t2 = 0; t2 < 4; ++t2)
        acc[s][t2] = __builtin_amdgcn_mfma_f32_16x16x32_bf16(af[s], bw[t2], acc[s][t2], 0, 0, 0);
    __builtin_amdgcn_s_setprio(0);

    ++bi; if (bi >= 3) bi = 0;
  }

  if (!resF && !resB && outB) {
    // coalesced epilogue: acc -> LDS C-tile (bf16, stride 136) -> 16B stores
    __syncthreads();
    bf16* sC = (bf16*)smem;
    constexpr int SCS = 136;
    #pragma unroll
    for (int t2 = 0; t2 < 4; ++t2) {
      int col = wn + t2 * 16 + l16;
      float bv = bias[n0 + col];
      #pragma unroll
      for (int s = 0; s < 4; ++s) {
        int rowb = wm + s * 16 + quad * 4;
        #pragma unroll
        for (int r2 = 0; r2 < 4; ++r2) {
          float v = acc[s][t2][r2] + bv;
          if (EPI == 1) v = 0.5f * v * (1.f + erff(v * 0.7071067811865475f));
          sC[(rowb + r2) * SCS + col] = f2b(v);
        }
      }
    }
    __syncthreads();
    int rl = tid >> 4, cl = tid & 15;
    #pragma unroll
    for (int i = 0; i < 8; ++i) {
      int row = i * 16 + rl;
      int gr = m0 + row;
      if (gr < M) {
        short8 vv = *reinterpret_cast<const short8*>(sC + row * SCS + cl * 8);
        *reinterpret_cast<short8*>(outB + (size_t)gr * Nc + n0 + cl * 8) = vv;
      }
    }
  } else {
    #pragma unroll
    for (int t2 = 0; t2 < 4; ++t2) {
      int col = n0 + wn + t2 * 16 + l16;
      float bv = bias[col];
      #pragma unroll
      for (int s = 0; s < 4; ++s) {
        int rowb = m0 + wm + s * 16 + quad * 4;
        #pragma unroll
        for (int r2 = 0; r2 < 4; ++r2) {
          int row = rowb + r2;
          if (row < M) {
            float v = acc[s][t2][r2] + bv;
            if (EPI == 1) v = 0.5f * v * (1.f + erff(v * 0.7071067811865475f));
            size_t idx = (size_t)row * Nc + col;
            if (resF) v += resF[idx];
            if (resB) v += b2f(resB[idx]);
            if (outF) outF[idx] = v;
            if (outB) outB[idx] = f2b(v);
          }
        }
      }
    }
  }
}

// ---------------- Kernel 5: MFMA attention, one block per (b, head) --------
// LDS caps occupancy at 2 blocks/CU (8 waves = 2/EU), so allow the register
// allocator the full 256-VGPR budget: pipelined K-fragment loads instead of
// load->wait->MFMA chains.
__global__ void __launch_bounds__(256, 2)
attn_mfma_kernel(const bf16* __restrict__ qkv, bf16* __restrict__ attn_o) {
  int bh = blockIdx.x;
  int h = bh % NH, b = bh / NH;
  int tid = threadIdx.x;
  int wave = tid >> 6, lane = tid & 63, quad = lane >> 4, l16 = lane & 15;

  __shared__ __align__(16) bf16 sVt[64][232];     // V^T: [d][m], m>=197 zero
  __shared__ __align__(16) bf16 sP[4][16][232];   // per-wave P: [q][m]; tail reused as O-scratch

  const bf16* base = qkv + (size_t)b * N * 2304 + h * 64;

  {
    int d = tid & 63;
    for (int m = tid >> 6; m < 224; m += 4) {
      sVt[d][m] = (m < N) ? base[(size_t)m * 2304 + 1536 + d] : f2b(0.f);
    }
  }
  __syncthreads();

  const float scale = 0.125f;   // 64^-0.5

  for (int qt = wave; qt < 13; qt += 4) {
    int qr = min(qt * 16 + l16, N - 1);
    const bf16* qp = base + (size_t)qr * 2304;
    short8 aq0 = *reinterpret_cast<const short8*>(qp + quad * 8);
    short8 aq1 = *reinterpret_cast<const short8*>(qp + 32 + quad * 8);

    floatx4 s[13];
    // depth-1 prefetched K-fragment pipeline
    short8 bk0c, bk1c;
    {
      int kr = min(l16, N - 1);
      const bf16* kp = base + (size_t)kr * 2304 + 768;
      bk0c = *reinterpret_cast<const short8*>(kp + quad * 8);
      bk1c = *reinterpret_cast<const short8*>(kp + 32 + quad * 8);
    }
    #pragma unroll
    for (int kt = 0; kt < 13; ++kt) {
      short8 bk0n, bk1n;
      if (kt < 12) {
        int kr = min((kt + 1) * 16 + l16, N - 1);
        const bf16* kp = base + (size_t)kr * 2304 + 768;
        bk0n = *reinterpret_cast<const short8*>(kp + quad * 8);
        bk1n = *reinterpret_cast<const short8*>(kp + 32 + quad * 8);
      }
      floatx4 acc = floatx4{0.f, 0.f, 0.f, 0.f};
      acc = __builtin_amdgcn_mfma_f32_16x16x32_bf16(aq0, bk0c, acc, 0, 0, 0);
      acc = __builtin_amdgcn_mfma_f32_16x16x32_bf16(aq1, bk1c, acc, 0, 0, 0);
      s[kt] = acc;
      if (kt < 12) { bk0c = bk0n; bk1c = bk1n; }
    }

    bool cv[13];
    #pragma unroll
    for (int kt = 0; kt < 13; ++kt) cv[kt] = (kt * 16 + l16) < N;

    float mx[4] = {-3.0e38f, -3.0e38f, -3.0e38f, -3.0e38f};
    #pragma unroll
    for (int kt = 0; kt < 13; ++kt) {
      #pragma unroll
      for (int r = 0; r < 4; ++r) {
        float sv = s[kt][r] * scale;
        s[kt][r] = sv;
        if (cv[kt]) mx[r] = fmaxf(mx[r], sv);
      }
    }
    #pragma unroll
    for (int off = 8; off >= 1; off >>= 1) {
      #pragma unroll
      for (int r = 0; r < 4; ++r) mx[r] = fmaxf(mx[r], __shfl_xor(mx[r], off, 64));
    }
    float sum[4] = {0.f, 0.f, 0.f, 0.f};
    #pragma unroll
    for (int kt = 0; kt < 13; ++kt) {
      #pragma unroll
      for (int r = 0; r < 4; ++r) {
        float e = cv[kt] ? __expf(s[kt][r] - mx[r]) : 0.f;
        s[kt][r] = e;
        sum[r] += e;
      }
    }
    #pragma unroll
    for (int off = 8; off >= 1; off >>= 1) {
      #pragma unroll
      for (int r = 0; r < 4; ++r) sum[r] += __shfl_xor(sum[r], off, 64);
    }
    float inv[4];
    #pragma unroll
    for (int r = 0; r < 4; ++r) inv[r] = 1.f / sum[r];

    #pragma unroll
    for (int kt = 0; kt < 13; ++kt) {
      #pragma unroll
      for (int r = 0; r < 4; ++r)
        sP[wave][quad * 4 + r][kt * 16 + l16] = f2b(s[kt][r]);
    }
    #pragma unroll
    for (int r = 0; r < 4; ++r)
      sP[wave][quad * 4 + r][208 + l16] = f2b(0.f);

    floatx4 o[4] = {floatx4{0,0,0,0}, floatx4{0,0,0,0}, floatx4{0,0,0,0}, floatx4{0,0,0,0}};
    #pragma unroll
    for (int c = 0; c < 7; ++c) {
      short8 ap = *reinterpret_cast<const short8*>(&sP[wave][l16][c * 32 + quad * 8]);
      #pragma unroll
      for (int t = 0; t < 4; ++t) {
        short8 bv = *reinterpret_cast<const short8*>(&sVt[t * 16 + l16][c * 32 + quad * 8]);
        o[t] = __builtin_amdgcn_mfma_f32_16x16x32_bf16(ap, bv, o[t], 0, 0, 0);
      }
    }

    // ---- coalesced output: o -> per-wave LDS scratch -> short8 stores ----
    // reuse this wave's sP region (PV ap-reads are complete after lgkmcnt(0);
    // wave-local, no barrier needed). scratch layout [16][72] bf16.
    asm volatile("s_waitcnt lgkmcnt(0)" ::: "memory");
    bf16* sO = &sP[wave][0][0];
    constexpr int SOS = 72;
    #pragma unroll
    for (int t = 0; t < 4; ++t) {
      #pragma unroll
      for (int r = 0; r < 4; ++r)
        sO[(quad * 4 + r) * SOS + t * 16 + l16] = f2b(o[t][r] * inv[r]);
    }
    asm volatile("s_waitcnt lgkmcnt(0)" ::: "memory");
    int orow = lane >> 3, ocol = (lane & 7) * 8;
    #pragma unroll
    for (int i = 0; i < 2; ++i) {
      int row = i * 8 + orow;
      int qrow = qt * 16 + row;
      if (qrow < N) {
        short8 vv = *reinterpret_cast<const short8*>(sO + row * SOS + ocol);
        *reinterpret_cast<short8*>(attn_o + ((size_t)b * N + qrow) * C + h * 64 + ocol) = vv;
      }
    }
    asm volatile("s_waitcnt lgkmcnt(0)" ::: "memory"); // scratch free before next qt reuses sP
  }
}

// ---------------- host-side orchestration ----------------------------------
extern "C" void kernel_launch(void* const* d_in, const int* in_sizes, int n_in,
                              void* d_out, int out_size, void* d_ws, size_t ws_size,
                              hipStream_t stream) {
  (void)in_sizes; (void)n_in; (void)out_size; (void)ws_size;
  const float* x       = (const float*)d_in[0];
  const float* norm1_g = (const float*)d_in[1];
  const float* norm1_b = (const float*)d_in[2];
  const float* qkv_w   = (const float*)d_in[3];
  const float* qkv_b   = (const float*)d_in[4];
  const float* proj_w  = (const float*)d_in[5];
  const float* proj_b  = (const float*)d_in[6];
  const float* norm2_g = (const float*)d_in[7];
  const float* norm2_b = (const float*)d_in[8];
  const float* fc1_w   = (const float*)d_in[9];
  const float* fc1_b   = (const float*)d_in[10];
  const float* fc2_w   = (const float*)d_in[11];
  const float* fc2_b   = (const float*)d_in[12];
  const float* f1_w    = (const float*)d_in[13];
  const float* f1_b    = (const float*)d_in[14];
  const float* f2_w    = (const float*)d_in[15];
  const float* f2_b    = (const float*)d_in[16];
  const float* v_w     = (const float*)d_in[17];
  const float* v_b     = (const float*)d_in[18];
  float* out = (float*)d_out;

  char* ws = (char*)d_ws;
  // ws layout (~131.2 MB). Activation buffers padded to MPAD=12672 rows.
  float* fusion7 = (float*)(ws + 0);                //    200,704
  bf16*  qkv_wf  = (bf16*)(ws + 262144);            //  3,538,944
  bf16*  proj_wf = (bf16*)(ws + 3801088);           //  1,179,648
  bf16*  fc1_wf  = (bf16*)(ws + 4980736);           //  4,718,592
  bf16*  fc2_wf  = (bf16*)(ws + 9699328);           //  4,718,592
  bf16*  ln1     = (bf16*)(ws + 14417920);          // 19,464,192 (MPAD x 768; reused: attn_o, ln2)
  bf16*  attn_o  = ln1;
  bf16*  ln2     = ln1;
  bf16*  qkvb    = (bf16*)(ws + 33882112);          // 77,856,768 (qkv MPADx2304; reused hbuf MPADx3072)
  bf16*  hbuf    = qkvb;
  bf16*  x2b     = (bf16*)(ws + 111738880);         // 19,464,192 (MPAD x 768 bf16) -> end 131,203,072

  cvt_wf_kernel<<<(2304 * 96 + 255) / 256, 256, 0, stream>>>(qkv_w, qkv_wf, 2304, 768);
  cvt_wf_kernel<<<(768 * 96 + 255) / 256, 256, 0, stream>>>(proj_w, proj_wf, 768, 768);
  cvt_wf_kernel<<<(3072 * 96 + 255) / 256, 256, 0, stream>>>(fc1_w, fc1_wf, 3072, 768);
  cvt_wf_kernel<<<(768 * 384 + 255) / 256, 256, 0, stream>>>(fc2_w, fc2_wf, 768, 3072);

  la_pool_kernel<<<B * 49, 256, 0, stream>>>(x, f1_w, f1_b, f2_w, f2_b, v_w, v_b, fusion7);
  gate_ln1_kernel<<<B * N, 256, 0, stream>>>(x, fusion7, norm1_g, norm1_b, ln1);
  // qkv: (M x 768) x (2304 x 768)^T -> bf16
  gemm128<0, 768><<<(2304 / 128) * MTP, 256, 0, stream>>>(
      ln1, qkv_wf, qkv_b, nullptr, nullptr, qkvb, nullptr, 2304);
  attn_mfma_kernel<<<B * NH, 256, 0, stream>>>(qkvb, attn_o);
  // proj + residual(x f32) -> x2b (bf16)
  gemm128<0, 768><<<(768 / 128) * MTP, 256, 0, stream>>>(
      attn_o, proj_wf, proj_b, x, nullptr, x2b, nullptr, 768);
  ln_bf16_kernel<<<M, 256, 0, stream>>>(x2b, norm2_g, norm2_b, ln2);
  // fc1 + gelu -> hbuf (bf16)
  gemm128<1, 768><<<(HID / 128) * MTP, 256, 0, stream>>>(
      ln2, fc1_wf, fc1_b, nullptr, nullptr, hbuf, nullptr, HID);
  // fc2 + residual(x2b bf16) -> out (f32)
  gemm128<0, 3072><<<(768 / 128) * MTP, 256, 0, stream>>>(
      hbuf, fc2_wf, fc2_b, nullptr, x2b, nullptr, out, 768);
}

// Round 5
// 541.484 us; speedup vs baseline: 1.2789x; 1.0106x over previous
//
#include <hip/hip_runtime.h>
#include <hip/hip_bf16.h>
#include <math.h>

using bf16 = __hip_bfloat16;
using short8 = __attribute__((ext_vector_type(8))) short;
using floatx4 = __attribute__((ext_vector_type(4))) float;

constexpr int B = 64;
constexpr int N = 197;
constexpr int C = 768;
constexpr int NH = 12;
constexpr int HD = 64;
constexpr int HID = 3072;
constexpr int M = B * N;          // 12608 = 197 * 64
constexpr int MPAD = 12672;       // 99 * 128
constexpr int MT = MPAD / 128;    // 99 M-tiles
constexpr int MTP = 104;          // padded to 8*13 for XCD swizzle
constexpr float EPS = 1e-5f;

__device__ __forceinline__ float b2f(bf16 v) { return __bfloat162float(v); }
__device__ __forceinline__ bf16 f2b(float v) { return __float2bfloat16(v); }

// async global->LDS, 16B/lane. HW dest = wave-uniform base + lane*16.
typedef const __attribute__((address_space(1))) unsigned int* gas1_t;
typedef __attribute__((address_space(3))) unsigned int* las3_t;
__device__ __forceinline__ void load_lds16(const bf16* g, bf16* l) {
  __builtin_amdgcn_global_load_lds((gas1_t)g, (las3_t)l, 16, 0, 0);
}

// ------- f32 weights -> bf16 MFMA-fragment layout --------------------------
__global__ void cvt_wf_kernel(const float* __restrict__ src, bf16* __restrict__ dst,
                              int Nc, int K) {
  int i = blockIdx.x * 256 + threadIdx.x;     // one thread per 8-elem group
  int total = Nc * (K >> 3);
  if (i >= total) return;
  int k8 = i % (K >> 3);
  int n  = i / (K >> 3);
  int kc = k8 >> 2, quad = k8 & 3;
  int nb = n >> 7, nn = n & 127, tp = nn >> 4, l = nn & 15;
  int KC = K >> 5;
  size_t di = (((size_t)nb * KC + kc) * 8 + tp) * 512 + quad * 128 + l * 8;
  const float* s = src + (size_t)n * K + k8 * 8;
  #pragma unroll
  for (int e = 0; e < 8; ++e) dst[di + e] = f2b(s[e]);
}

// ---------------- block-wide sum over 256 threads (4 waves) ----------------
__device__ __forceinline__ float block_sum(float v, float* red) {
  #pragma unroll
  for (int off = 32; off >= 1; off >>= 1) v += __shfl_xor(v, off, 64);
  int w = threadIdx.x >> 6;
  if ((threadIdx.x & 63) == 0) red[w] = v;
  __syncthreads();
  float r = red[0] + red[1] + red[2] + red[3];
  __syncthreads();
  return r;
}

// ---------------- Kernel 1: LA pooling + channel MLP + fusion --------------
__global__ void la_pool_kernel(const float* __restrict__ x,
                               const float* __restrict__ f1w, const float* __restrict__ f1bias,
                               const float* __restrict__ f2w, const float* __restrict__ f2bias,
                               const float* __restrict__ vw,  const float* __restrict__ vbias,
                               float* __restrict__ fusion7) {
  int blk = blockIdx.x;
  int b = blk / 49, p = blk % 49;
  int h7 = p / 7, w7 = p % 7;
  int tid = threadIdx.x;
  int head = tid >> 4;     // 0..15
  int j = tid & 15;        // 0..15

  float sum = 0.f, mx = -3.0e38f;
  #pragma unroll
  for (int a = 0; a < 2; ++a) {
    #pragma unroll
    for (int bb = 0; bb < 2; ++bb) {
      int tok = 1 + (2 * h7 + a) * 14 + (2 * w7 + bb);
      const float* row = x + ((size_t)b * N + tok) * C + head * 48;
      #pragma unroll
      for (int s = 0; s < 3; ++s) {
        float v = row[j + 16 * s];
        sum += v;
        mx = fmaxf(mx, v);
      }
    }
  }
  #pragma unroll
  for (int off = 8; off >= 1; off >>= 1) {
    sum += __shfl_xor(sum, off, 64);
    mx = fmaxf(mx, __shfl_xor(mx, off, 64));
  }
  __shared__ float s_mean[16], s_max[16];
  if (j == 0) { s_mean[head] = sum / 192.f; s_max[head] = mx; }
  __syncthreads();
  if (tid < 16) {
    float hm = f1bias[0], hx = hm;
    #pragma unroll
    for (int h = 0; h < 16; ++h) {
      float w = f1w[h];
      hm += s_mean[h] * w;
      hx += s_max[h] * w;
    }
    hm = fmaxf(hm, 0.f);
    hx = fmaxf(hx, 0.f);
    float w2 = f2w[tid], b2v = f2bias[tid];
    float m   = hm * w2 + b2v;
    float mxv = hx * w2 + b2v;
    float fus = vw[0] * m + vw[1] * mxv + vbias[0];
    fusion7[((size_t)b * 16 + tid) * 49 + p] = fus;
  }
}

// ---------------- Kernel 2: gate (bilinear resize + sigmoid) + LN1 ---------
__global__ void gate_ln1_kernel(const float* __restrict__ x, const float* __restrict__ fusion7,
                                const float* __restrict__ g, const float* __restrict__ beta,
                                bf16* __restrict__ ln1) {
  int blk = blockIdx.x;
  int b = blk / N, n = blk % N;
  int tid = threadIdx.x;
  __shared__ float gates[16];
  __shared__ float red[4];

  if (tid < 16) {
    if (n > 0) {
      int hh = (n - 1) / 14, ww = (n - 1) % 14;
      float ch = fminf(fmaxf(hh * 0.5f - 0.25f, 0.f), 6.f);
      float cw = fminf(fmaxf(ww * 0.5f - 0.25f, 0.f), 6.f);
      int h0 = (int)floorf(ch); int h1 = min(h0 + 1, 6); float fh = ch - (float)h0;
      int w0 = (int)floorf(cw); int w1 = min(w0 + 1, 6); float fw = cw - (float)w0;
      const float* fp = fusion7 + ((size_t)b * 16 + tid) * 49;
      float v00 = fp[h0 * 7 + w0], v01 = fp[h0 * 7 + w1];
      float v10 = fp[h1 * 7 + w0], v11 = fp[h1 * 7 + w1];
      float v = (1.f - fh) * ((1.f - fw) * v00 + fw * v01)
              + fh        * ((1.f - fw) * v10 + fw * v11);
      gates[tid] = 1.f / (1.f + expf(-v));
    } else {
      gates[tid] = 0.f;   // cls token: multiplier (1+0) == identity
    }
  }
  __syncthreads();

  const float* xr = x + ((size_t)b * N + n) * C;
  float v[3];
  #pragma unroll
  for (int s = 0; s < 3; ++s) {
    int c = tid + 256 * s;
    v[s] = xr[c] * (1.f + gates[c / 48]);
  }
  float mu = block_sum(v[0] + v[1] + v[2], red) * (1.f / 768.f);
  float d0 = v[0] - mu, d1 = v[1] - mu, d2 = v[2] - mu;
  float var = block_sum(d0 * d0 + d1 * d1 + d2 * d2, red) * (1.f / 768.f);
  float rs = rsqrtf(var + EPS);
  bf16* orow = ln1 + ((size_t)b * N + n) * C;
  #pragma unroll
  for (int s = 0; s < 3; ++s) {
    int c = tid + 256 * s;
    orow[c] = f2b((v[s] - mu) * rs * g[c] + beta[c]);
  }
}

// ---------------- Kernel 3: LN over bf16 input -> bf16 ---------------------
__global__ void ln_bf16_kernel(const bf16* __restrict__ xin,
                               const float* __restrict__ g, const float* __restrict__ beta,
                               bf16* __restrict__ out) {
  int row = blockIdx.x;
  int tid = threadIdx.x;
  __shared__ float red[4];
  const bf16* xr = xin + (size_t)row * C;
  float v[3];
  #pragma unroll
  for (int s = 0; s < 3; ++s) v[s] = b2f(xr[tid + 256 * s]);
  float mu = block_sum(v[0] + v[1] + v[2], red) * (1.f / 768.f);
  float d0 = v[0] - mu, d1 = v[1] - mu, d2 = v[2] - mu;
  float var = block_sum(d0 * d0 + d1 * d1 + d2 * d2, red) * (1.f / 768.f);
  float rs = rsqrtf(var + EPS);
  bf16* orow = out + (size_t)row * C;
  #pragma unroll
  for (int s = 0; s < 3; ++s) {
    int c = tid + 256 * s;
    orow[c] = f2b((v[s] - mu) * rs * g[c] + beta[c]);
  }
}

// ---------------- Kernel 4: 128x128 tile, counted-vmcnt pipeline -----------
// T4 schedule + quality pass (round 4), with the A-fragment address bug
// fixed: read base must include the per-lane l16*32 row term.
template <int EPI, int K>
__global__ void __launch_bounds__(256, 3)
gemm128(const bf16* __restrict__ A, const bf16* __restrict__ Wf,
        const float* __restrict__ bias,
        const float* __restrict__ resF, const bf16* __restrict__ resB,
        bf16* __restrict__ outB, float* __restrict__ outF, int Nc) {
  constexpr int KC = K >> 5;
  static_assert(KC % 3 == 0, "KC must be divisible by 3 for the unroll");
  constexpr int CW = (K == 768) ? 6 : 3;   // column-chunk width (divides nx)
  constexpr int PERCH = 13 * CW;           // blocks per chunk per XCD
  int nx = Nc >> 7;
  int g = blockIdx.x;
  int c = g & 7;                 // XCD
  int t = g >> 3;                // stream index within XCD, [0, 13*nx)
  int ch = t / PERCH;
  int r  = t % PERCH;
  int j  = r / CW;
  int x  = ch * CW + (r % CW);
  int y  = c + 8 * j;
  if (y >= MT) return;                 // padded tail
  int m0 = y * 128;
  int n0 = x * 128;

  // 48 KB: 3 x 8KB A buffers + 3 x 8KB B buffers; reused as C-tile
  __shared__ __align__(16) char smem[49152];
  bf16* sA = (bf16*)smem;                  // [3][128*32]
  bf16* sB = (bf16*)(smem + 24576);        // [3][8*512]

  int tid = threadIdx.x;
  int wave = tid >> 6, lane = tid & 63, quad = lane >> 4, l16 = lane & 15;

  int ln16 = lane >> 2, seg = lane & 3;
  int sw = seg ^ ((ln16 >> 1) & 3);                 // swizzled chunk in row
  const bf16* gA = A + (size_t)(m0 + wave * 32 + ln16) * K + sw * 8;

  const bf16* gB = Wf + ((size_t)(n0 >> 7) * KC) * 4096 + (size_t)(wave * 2) * 512 + lane * 8;

  int wm = (wave & 1) * 64, wn = (wave >> 1) * 64;  // wave quadrant
  int csw = (l16 >> 1) & 3;                         // fragment-read swizzle
  int tp0 = wn >> 4;                                // first B slab for wave

  floatx4 acc[4][4] = {};

  // per-wave static LDS staging bases
  bf16* dA0 = sA + (wave * 32) * 32;
  bf16* dB0 = sB + (wave * 2) * 512;

  // stage(chunk at gAs/gBs) into buffer at compile-time offset bufOff
  auto stageTo = [&](const bf16* gAs, const bf16* gBs, int bufOff) {
    load_lds16(gAs, dA0 + bufOff);
    load_lds16(gAs + (size_t)16 * K, dA0 + bufOff + 16 * 32);
    load_lds16(gBs, dB0 + bufOff);
    load_lds16(gBs + 512, dB0 + bufOff + 512);
  };

  // prologue: chunks 0,1 -> buffers 0,1 (8 outstanding per wave)
  stageTo(gA, gB, 0);
  stageTo(gA + 32, gB + 4096, 4096);

  // stage cursors point at chunk 2
  const bf16* gAs = gA + 64;
  const bf16* gBs = gB + 8192;

  // fragment read bases (FIX: + l16*32 per-lane row term)
  const bf16* aRd = sA + (wm + l16) * 32 + (quad ^ csw) * 8;  // + s*16*32 + buf
  const bf16* bRd = sB + tp0 * 512 + lane * 8;                // + t2*512 + buf

  auto body = [&](int bufOff, int stageBufOff, bool doStage, bool lastIter) {
    if (lastIter) {
      asm volatile("s_waitcnt vmcnt(0) lgkmcnt(0)" ::: "memory");
    } else {
      asm volatile("s_waitcnt vmcnt(4) lgkmcnt(0)" ::: "memory");
    }
    __builtin_amdgcn_s_barrier();
    __builtin_amdgcn_sched_barrier(0);

    // ds_reads first (static addresses)
    short8 bw[4];
    #pragma unroll
    for (int t2 = 0; t2 < 4; ++t2)
      bw[t2] = *reinterpret_cast<const short8*>(bRd + bufOff + t2 * 512);
    short8 af[4];
    #pragma unroll
    for (int s = 0; s < 4; ++s)
      af[s] = *reinterpret_cast<const short8*>(aRd + bufOff + s * 16 * 32);

    if (doStage) {
      stageTo(gAs, gBs, stageBufOff);
      gAs += 32;
      gBs += 4096;
    }

    __builtin_amdgcn_s_setprio(1);
    #pragma unroll
    for (int s = 0; s < 4; ++s)
      #pragma unroll
      for (int t2 = 0; t2 < 4; ++t2)
        acc[s][t2] = __builtin_amdgcn_mfma_f32_16x16x32_bf16(af[s], bw[t2], acc[s][t2], 0, 0, 0);
    __builtin_amdgcn_s_setprio(0);
  };

  for (int kc0 = 0; kc0 < KC; kc0 += 3) {
    bool lastGrp = (kc0 + 3 >= KC);
    body(0,    8192, true,      false);          // kc0+0 reads buf0, stages buf2
    body(4096, 0,    !lastGrp,  false);          // kc0+1 reads buf1, stages buf0
    body(8192, 4096, !lastGrp,  lastGrp);        // kc0+2 reads buf2, stages buf1
  }

  if (!resF && !resB && outB) {
    // coalesced epilogue: acc -> LDS C-tile (bf16, stride 136) -> 16B stores
    __syncthreads();
    bf16* sC = (bf16*)smem;
    constexpr int SCS = 136;
    #pragma unroll
    for (int t2 = 0; t2 < 4; ++t2) {
      int col = wn + t2 * 16 + l16;
      float bv = bias[n0 + col];
      #pragma unroll
      for (int s = 0; s < 4; ++s) {
        int rowb = wm + s * 16 + quad * 4;
        #pragma unroll
        for (int r2 = 0; r2 < 4; ++r2) {
          float v = acc[s][t2][r2] + bv;
          if (EPI == 1) v = 0.5f * v * (1.f + erff(v * 0.7071067811865475f));
          sC[(rowb + r2) * SCS + col] = f2b(v);
        }
      }
    }
    __syncthreads();
    int rl = tid >> 4, cl = tid & 15;
    #pragma unroll
    for (int i = 0; i < 8; ++i) {
      int row = i * 16 + rl;
      int gr = m0 + row;
      if (gr < M) {
        short8 vv = *reinterpret_cast<const short8*>(sC + row * SCS + cl * 8);
        *reinterpret_cast<short8*>(outB + (size_t)gr * Nc + n0 + cl * 8) = vv;
      }
    }
  } else {
    #pragma unroll
    for (int t2 = 0; t2 < 4; ++t2) {
      int col = n0 + wn + t2 * 16 + l16;
      float bv = bias[col];
      #pragma unroll
      for (int s = 0; s < 4; ++s) {
        int rowb = m0 + wm + s * 16 + quad * 4;
        #pragma unroll
        for (int r2 = 0; r2 < 4; ++r2) {
          int row = rowb + r2;
          if (row < M) {
            float v = acc[s][t2][r2] + bv;
            if (EPI == 1) v = 0.5f * v * (1.f + erff(v * 0.7071067811865475f));
            size_t idx = (size_t)row * Nc + col;
            if (resF) v += resF[idx];
            if (resB) v += b2f(resB[idx]);
            if (outF) outF[idx] = v;
            if (outB) outB[idx] = f2b(v);
          }
        }
      }
    }
  }
}

// ---------------- Kernel 5: MFMA attention, one block per (b, head) --------
// (unchanged from round 3)
__global__ void __launch_bounds__(256, 2)
attn_mfma_kernel(const bf16* __restrict__ qkv, bf16* __restrict__ attn_o) {
  int bh = blockIdx.x;
  int h = bh % NH, b = bh / NH;
  int tid = threadIdx.x;
  int wave = tid >> 6, lane = tid & 63, quad = lane >> 4, l16 = lane & 15;

  __shared__ __align__(16) bf16 sVt[64][232];     // V^T: [d][m], m>=197 zero
  __shared__ __align__(16) bf16 sP[4][16][232];   // per-wave P: [q][m]; tail reused as O-scratch

  const bf16* base = qkv + (size_t)b * N * 2304 + h * 64;

  {
    int d = tid & 63;
    for (int m = tid >> 6; m < 224; m += 4) {
      sVt[d][m] = (m < N) ? base[(size_t)m * 2304 + 1536 + d] : f2b(0.f);
    }
  }
  __syncthreads();

  const float scale = 0.125f;   // 64^-0.5

  for (int qt = wave; qt < 13; qt += 4) {
    int qr = min(qt * 16 + l16, N - 1);
    const bf16* qp = base + (size_t)qr * 2304;
    short8 aq0 = *reinterpret_cast<const short8*>(qp + quad * 8);
    short8 aq1 = *reinterpret_cast<const short8*>(qp + 32 + quad * 8);

    floatx4 s[13];
    // depth-1 prefetched K-fragment pipeline
    short8 bk0c, bk1c;
    {
      int kr = min(l16, N - 1);
      const bf16* kp = base + (size_t)kr * 2304 + 768;
      bk0c = *reinterpret_cast<const short8*>(kp + quad * 8);
      bk1c = *reinterpret_cast<const short8*>(kp + 32 + quad * 8);
    }
    #pragma unroll
    for (int kt = 0; kt < 13; ++kt) {
      short8 bk0n, bk1n;
      if (kt < 12) {
        int kr = min((kt + 1) * 16 + l16, N - 1);
        const bf16* kp = base + (size_t)kr * 2304 + 768;
        bk0n = *reinterpret_cast<const short8*>(kp + quad * 8);
        bk1n = *reinterpret_cast<const short8*>(kp + 32 + quad * 8);
      }
      floatx4 acc = floatx4{0.f, 0.f, 0.f, 0.f};
      acc = __builtin_amdgcn_mfma_f32_16x16x32_bf16(aq0, bk0c, acc, 0, 0, 0);
      acc = __builtin_amdgcn_mfma_f32_16x16x32_bf16(aq1, bk1c, acc, 0, 0, 0);
      s[kt] = acc;
      if (kt < 12) { bk0c = bk0n; bk1c = bk1n; }
    }

    bool cv[13];
    #pragma unroll
    for (int kt = 0; kt < 13; ++kt) cv[kt] = (kt * 16 + l16) < N;

    float mx[4] = {-3.0e38f, -3.0e38f, -3.0e38f, -3.0e38f};
    #pragma unroll
    for (int kt = 0; kt < 13; ++kt) {
      #pragma unroll
      for (int r = 0; r < 4; ++r) {
        float sv = s[kt][r] * scale;
        s[kt][r] = sv;
        if (cv[kt]) mx[r] = fmaxf(mx[r], sv);
      }
    }
    #pragma unroll
    for (int off = 8; off >= 1; off >>= 1) {
      #pragma unroll
      for (int r = 0; r < 4; ++r) mx[r] = fmaxf(mx[r], __shfl_xor(mx[r], off, 64));
    }
    float sum[4] = {0.f, 0.f, 0.f, 0.f};
    #pragma unroll
    for (int kt = 0; kt < 13; ++kt) {
      #pragma unroll
      for (int r = 0; r < 4; ++r) {
        float e = cv[kt] ? __expf(s[kt][r] - mx[r]) : 0.f;
        s[kt][r] = e;
        sum[r] += e;
      }
    }
    #pragma unroll
    for (int off = 8; off >= 1; off >>= 1) {
      #pragma unroll
      for (int r = 0; r < 4; ++r) sum[r] += __shfl_xor(sum[r], off, 64);
    }
    float inv[4];
    #pragma unroll
    for (int r = 0; r < 4; ++r) inv[r] = 1.f / sum[r];

    #pragma unroll
    for (int kt = 0; kt < 13; ++kt) {
      #pragma unroll
      for (int r = 0; r < 4; ++r)
        sP[wave][quad * 4 + r][kt * 16 + l16] = f2b(s[kt][r]);
    }
    #pragma unroll
    for (int r = 0; r < 4; ++r)
      sP[wave][quad * 4 + r][208 + l16] = f2b(0.f);

    floatx4 o[4] = {floatx4{0,0,0,0}, floatx4{0,0,0,0}, floatx4{0,0,0,0}, floatx4{0,0,0,0}};
    #pragma unroll
    for (int c = 0; c < 7; ++c) {
      short8 ap = *reinterpret_cast<const short8*>(&sP[wave][l16][c * 32 + quad * 8]);
      #pragma unroll
      for (int t = 0; t < 4; ++t) {
        short8 bv = *reinterpret_cast<const short8*>(&sVt[t * 16 + l16][c * 32 + quad * 8]);
        o[t] = __builtin_amdgcn_mfma_f32_16x16x32_bf16(ap, bv, o[t], 0, 0, 0);
      }
    }

    // ---- coalesced output: o -> per-wave LDS scratch -> short8 stores ----
    asm volatile("s_waitcnt lgkmcnt(0)" ::: "memory");
    bf16* sO = &sP[wave][0][0];
    constexpr int SOS = 72;
    #pragma unroll
    for (int t = 0; t < 4; ++t) {
      #pragma unroll
      for (int r = 0; r < 4; ++r)
        sO[(quad * 4 + r) * SOS + t * 16 + l16] = f2b(o[t][r] * inv[r]);
    }
    asm volatile("s_waitcnt lgkmcnt(0)" ::: "memory");
    int orow = lane >> 3, ocol = (lane & 7) * 8;
    #pragma unroll
    for (int i = 0; i < 2; ++i) {
      int row = i * 8 + orow;
      int qrow = qt * 16 + row;
      if (qrow < N) {
        short8 vv = *reinterpret_cast<const short8*>(sO + row * SOS + ocol);
        *reinterpret_cast<short8*>(attn_o + ((size_t)b * N + qrow) * C + h * 64 + ocol) = vv;
      }
    }
    asm volatile("s_waitcnt lgkmcnt(0)" ::: "memory"); // scratch free before next qt reuses sP
  }
}

// ---------------- host-side orchestration ----------------------------------
extern "C" void kernel_launch(void* const* d_in, const int* in_sizes, int n_in,
                              void* d_out, int out_size, void* d_ws, size_t ws_size,
                              hipStream_t stream) {
  (void)in_sizes; (void)n_in; (void)out_size; (void)ws_size;
  const float* x       = (const float*)d_in[0];
  const float* norm1_g = (const float*)d_in[1];
  const float* norm1_b = (const float*)d_in[2];
  const float* qkv_w   = (const float*)d_in[3];
  const float* qkv_b   = (const float*)d_in[4];
  const float* proj_w  = (const float*)d_in[5];
  const float* proj_b  = (const float*)d_in[6];
  const float* norm2_g = (const float*)d_in[7];
  const float* norm2_b = (const float*)d_in[8];
  const float* fc1_w   = (const float*)d_in[9];
  const float* fc1_b   = (const float*)d_in[10];
  const float* fc2_w   = (const float*)d_in[11];
  const float* fc2_b   = (const float*)d_in[12];
  const float* f1_w    = (const float*)d_in[13];
  const float* f1_b    = (const float*)d_in[14];
  const float* f2_w    = (const float*)d_in[15];
  const float* f2_b    = (const float*)d_in[16];
  const float* v_w     = (const float*)d_in[17];
  const float* v_b     = (const float*)d_in[18];
  float* out = (float*)d_out;

  char* ws = (char*)d_ws;
  // ws layout (~131.2 MB). Activation buffers padded to MPAD=12672 rows.
  float* fusion7 = (float*)(ws + 0);                //    200,704
  bf16*  qkv_wf  = (bf16*)(ws + 262144);            //  3,538,944
  bf16*  proj_wf = (bf16*)(ws + 3801088);           //  1,179,648
  bf16*  fc1_wf  = (bf16*)(ws + 4980736);           //  4,718,592
  bf16*  fc2_wf  = (bf16*)(ws + 9699328);           //  4,718,592
  bf16*  ln1     = (bf16*)(ws + 14417920);          // 19,464,192 (MPAD x 768; reused: attn_o, ln2)
  bf16*  attn_o  = ln1;
  bf16*  ln2     = ln1;
  bf16*  qkvb    = (bf16*)(ws + 33882112);          // 77,856,768 (qkv MPADx2304; reused hbuf MPADx3072)
  bf16*  hbuf    = qkvb;
  bf16*  x2b     = (bf16*)(ws + 111738880);         // 19,464,192 (MPAD x 768 bf16) -> end 131,203,072

  cvt_wf_kernel<<<(2304 * 96 + 255) / 256, 256, 0, stream>>>(qkv_w, qkv_wf, 2304, 768);
  cvt_wf_kernel<<<(768 * 96 + 255) / 256, 256, 0, stream>>>(proj_w, proj_wf, 768, 768);
  cvt_wf_kernel<<<(3072 * 96 + 255) / 256, 256, 0, stream>>>(fc1_w, fc1_wf, 3072, 768);
  cvt_wf_kernel<<<(768 * 384 + 255) / 256, 256, 0, stream>>>(fc2_w, fc2_wf, 768, 3072);

  la_pool_kernel<<<B * 49, 256, 0, stream>>>(x, f1_w, f1_b, f2_w, f2_b, v_w, v_b, fusion7);
  gate_ln1_kernel<<<B * N, 256, 0, stream>>>(x, fusion7, norm1_g, norm1_b, ln1);
  // qkv: (M x 768) x (2304 x 768)^T -> bf16
  gemm128<0, 768><<<(2304 / 128) * MTP, 256, 0, stream>>>(
      ln1, qkv_wf, qkv_b, nullptr, nullptr, qkvb, nullptr, 2304);
  attn_mfma_kernel<<<B * NH, 256, 0, stream>>>(qkvb, attn_o);
  // proj + residual(x f32) -> x2b (bf16)
  gemm128<0, 768><<<(768 / 128) * MTP, 256, 0, stream>>>(
      attn_o, proj_wf, proj_b, x, nullptr, x2b, nullptr, 768);
  ln_bf16_kernel<<<M, 256, 0, stream>>>(x2b, norm2_g, norm2_b, ln2);
  // fc1 + gelu -> hbuf (bf16)
  gemm128<1, 768><<<(HID / 128) * MTP, 256, 0, stream>>>(
      ln2, fc1_wf, fc1_b, nullptr, nullptr, hbuf, nullptr, HID);
  // fc2 + residual(x2b bf16) -> out (f32)
  gemm128<0, 3072><<<(768 / 128) * MTP, 256, 0, stream>>>(
      hbuf, fc2_wf, fc2_b, nullptr, x2b, nullptr, out, 768);
}